// Round 7
// baseline (664.591 us; speedup 1.0000x reference)
//
#include <hip/hip_runtime.h>
#include <math.h>

// ---------------------------------------------------------------------------
// PseqStepV3: 3-layer TransformerConv (heads=1), N=50000, E=800000, D=64.
//   setup: detect edge dtype; build CSR by dst:
//     hist_extract (histogram + compact src/dst arrays) -> multi-block scan
//     -> partitioned scatter (64 WGs, one node-range each, LDS cursors;
//        kills the 16x cross-XCD write amplification seen in R5/R6)
//   per layer: fused q/kv/s GEMM (readlane broadcast, 16 rows/wave,
//              split-c 32KB LDS; k fp32 + v bf16 packed in one 384B row)
//              -> fused online-softmax aggregation (single-row kv gather)
// ---------------------------------------------------------------------------

#define D64 64
#define KVF 96     // floats per kv row: 64 fp32 k + 32 floats (64 bf16) v
#define NPART 64   // scatter partitions (one workgroup each)

__device__ __forceinline__ unsigned short bf16_rne(float f) {
    unsigned int u = __float_as_uint(f);
    u += 0x7FFFu + ((u >> 16) & 1u);
    return (unsigned short)(u >> 16);
}

// ---- edge_index format detection: int64 rows have zero high words ----------
__global__ void detect_fmt(const int* __restrict__ ei, int nchecks, int* flag) {
    int t = blockIdx.x * blockDim.x + threadIdx.x;
    int acc = 0;
    for (int i = t; i < nchecks; i += blockDim.x * gridDim.x)
        acc |= ei[2 * i + 1];
    if (acc) atomicOr(flag, 1);   // nonzero => plain int32 layout
}

__device__ __forceinline__ int load_src(const int* ei, int e, int E, int is64) {
    return is64 ? ei[2 * e] : ei[e];
}
__device__ __forceinline__ int load_dst(const int* ei, int e, int E, int is64) {
    return is64 ? ei[2 * E + 2 * e] : ei[E + e];
}

// ---- CSR build -------------------------------------------------------------
// histogram + compact extraction (sequential writes; dstc/srcc feed scatter)
__global__ void hist_extract(const int* __restrict__ ei, int* __restrict__ counts,
                             int* __restrict__ dstc, int* __restrict__ srcc,
                             int E, const int* __restrict__ flag) {
    int e = blockIdx.x * blockDim.x + threadIdx.x;
    if (e >= E) return;
    int is64 = (*flag == 0);
    int s = load_src(ei, e, E, is64);
    int d = load_dst(ei, e, E, is64);
    dstc[e] = d;
    srcc[e] = s;
    atomicAdd(&counts[d], 1);
}

__global__ void scan_blocks(const int* __restrict__ counts, int* __restrict__ partial,
                            int* __restrict__ blockSums, int n) {
    int tid = threadIdx.x;                 // 256
    int base = blockIdx.x * 1024 + tid * 4;
    int4 c = make_int4(0, 0, 0, 0);
    if (base + 3 < n) c = *(const int4*)&counts[base];
    else {
        if (base + 0 < n) c.x = counts[base + 0];
        if (base + 1 < n) c.y = counts[base + 1];
        if (base + 2 < n) c.z = counts[base + 2];
        if (base + 3 < n) c.w = counts[base + 3];
    }
    int s1 = c.x, s2 = s1 + c.y, s3 = s2 + c.z, s4 = s3 + c.w;
    int lane = tid & 63, wave = tid >> 6;
    int v = s4;
#pragma unroll
    for (int off = 1; off < 64; off <<= 1) {
        int t = __shfl_up(v, off);
        if (lane >= off) v += t;
    }
    __shared__ int wsum[4];
    if (lane == 63) wsum[wave] = v;
    __syncthreads();
    int wpre = 0;
    for (int w = 0; w < wave; ++w) wpre += wsum[w];
    int pre = wpre + v - s4;
    if (base + 0 < n) partial[base + 0] = pre + s1;
    if (base + 1 < n) partial[base + 1] = pre + s2;
    if (base + 2 < n) partial[base + 2] = pre + s3;
    if (base + 3 < n) partial[base + 3] = pre + s4;
    if (tid == 255) blockSums[blockIdx.x] = wsum[0] + wsum[1] + wsum[2] + wsum[3];
}

__global__ void scan_sums(int* __restrict__ bs, int nb) {
    int lane = threadIdx.x;                // 64
    int carry = 0;
    for (int b0 = 0; b0 < nb; b0 += 64) {
        int i = b0 + lane;
        int val = (i < nb) ? bs[i] : 0;
        int v = val;
#pragma unroll
        for (int off = 1; off < 64; off <<= 1) {
            int t = __shfl_up(v, off);
            if (lane >= off) v += t;
        }
        if (i < nb) bs[i] = carry + v - val;   // exclusive
        carry += __shfl(v, 63);
    }
}

__global__ void scan_final(const int* __restrict__ counts, const int* __restrict__ partial,
                           const int* __restrict__ bs, int* __restrict__ offsets,
                           int* __restrict__ nxt, int n) {
    int i = blockIdx.x * 256 + threadIdx.x;
    if (i >= n) return;
    int inc = partial[i] + bs[i >> 10];
    offsets[i + 1] = inc;
    nxt[i] = inc - counts[i];
    if (i == 0) offsets[0] = 0;
}

// partitioned scatter: WG p owns node range [p*npp, p*npp+npp). Cursors live
// in LDS (fast atomics, zero cross-XCD line sharing); csr_src lines are
// written by exactly one WG -> no write-allocate amplification.
__global__ void scatter_part(const int* __restrict__ dstc, const int* __restrict__ srcc,
                             const int* __restrict__ nxt, int* __restrict__ csr_src,
                             int E, int N) {
    extern __shared__ int cur[];
    int p = blockIdx.x;
    int npp = (N + NPART - 1) / NPART;
    int n0 = p * npp;
    int cnt = N - n0; if (cnt > npp) cnt = npp;
    if (cnt <= 0) return;
    for (int i = threadIdx.x; i < cnt; i += blockDim.x) cur[i] = nxt[n0 + i];
    __syncthreads();
    for (int e = threadIdx.x; e < E; e += blockDim.x) {
        int d = dstc[e] - n0;
        if ((unsigned)d < (unsigned)cnt) {
            int pos = atomicAdd(&cur[d], 1);
            csr_src[pos] = srcc[e];
        }
    }
}

// ---- fused q/kv/s GEMM -----------------------------------------------------
// Wave: 16 rows x 4 matrices. x broadcast via readlane (SGPR path); weight
// quad via one ds_read_b128 per c-step (1 LDS op / 64 FMAs). c-loop split in
// two 32-channel halves so LDS = 32 KiB. Outputs: q fp32, s fp32, and a packed
// kv row per node: 64 fp32 k + 64 bf16 v = 384 B contiguous (one-gather agg).
__launch_bounds__(256)
__global__ void gemm_qkvs(const float* __restrict__ x,
                          const float* __restrict__ Wq, const float* __restrict__ bq,
                          const float* __restrict__ Wk, const float* __restrict__ bk,
                          const float* __restrict__ Wv, const float* __restrict__ bv,
                          const float* __restrict__ Ws, const float* __restrict__ bs,
                          float* __restrict__ q, float* __restrict__ kv,
                          float* __restrict__ s, int n) {
    __shared__ float Wh[32 * 256];  // 32 KiB: Wh[c][lane][4] for one c-half
    int tid = threadIdx.x;
    int wave = tid >> 6, lane = tid & 63;
    int row0 = blockIdx.x * 64 + wave * 16;

    float xr[16];
#pragma unroll
    for (int j = 0; j < 16; ++j)
        xr[j] = (row0 + j < n) ? x[(size_t)(row0 + j) * D64 + lane] : 0.f;

    float bqv = bq[lane], bkv = bk[lane], bvv = bv[lane], bsv = bs[lane];
    float aq[16], ak[16], av[16], as_[16];
#pragma unroll
    for (int j = 0; j < 16; ++j) { aq[j] = bqv; ak[j] = bkv; av[j] = bvv; as_[j] = bsv; }

    for (int half = 0; half < 2; ++half) {
        int c0 = half * 32;
        for (int i = tid; i < 32 * 64; i += 256) {
            int c = i >> 6, l = i & 63;
            int gi = (c0 + c) * 64 + l;
            float4 wv4;
            wv4.x = Wq[gi]; wv4.y = Wk[gi]; wv4.z = Wv[gi]; wv4.w = Ws[gi];
            *(float4*)&Wh[c * 256 + l * 4] = wv4;
        }
        __syncthreads();
#pragma unroll 4
        for (int cc = 0; cc < 32; ++cc) {
            int c = c0 + cc;
            const float4 w = *(const float4*)&Wh[cc * 256 + lane * 4];
#pragma unroll
            for (int j = 0; j < 16; ++j) {
                float xs = __int_as_float(
                    __builtin_amdgcn_readlane(__float_as_int(xr[j]), c));
                aq[j] += xs * w.x;
                ak[j] += xs * w.y;
                av[j] += xs * w.z;
                as_[j] += xs * w.w;
            }
        }
        __syncthreads();
    }
#pragma unroll
    for (int j = 0; j < 16; ++j) {
        if (row0 + j < n) {
            size_t o = (size_t)(row0 + j) * D64 + lane;
            q[o] = aq[j]; s[o] = as_[j];
            size_t rb = (size_t)(row0 + j) * KVF;
            kv[rb + lane] = ak[j];                         // k fp32, 256B row
            unsigned short* vp = (unsigned short*)(kv + rb + 64);
            vp[lane] = bf16_rne(av[j]);                    // v bf16, 128B row
        }
    }
}

// ---- fused edge-score + online-softmax aggregation + epilogue --------------
// Wave = 1 node. 8 groups x 8 lanes; group owns one edge/iter, lane l8 owns
// channels [8*l8, 8*l8+8). Per edge one contiguous 384B kv-row gather:
// 2x float4 k (fp32) + 1x float4 = 8x bf16 v. 2-deep load pipeline. Online
// (m, den, acc) per group; butterfly-merged over xor 8/16/32.
// MODE 1: out = silu(t)   MODE 2: out = silu(t + xin)   MODE 3: out = t + 0.1*z
template <int MODE>
__launch_bounds__(256)
__global__ void agg_fused(const float* __restrict__ q, const float* __restrict__ kv,
                          const int* __restrict__ csr_src,
                          const int* __restrict__ offsets,
                          const float* __restrict__ sbuf, const float* __restrict__ xin,
                          const float* __restrict__ z, float* __restrict__ out, int n) {
    int node = blockIdx.x * 4 + (threadIdx.x >> 6);
    if (node >= n) return;
    int lane = threadIdx.x & 63;
    int grp = lane >> 3, l8 = lane & 7;
    int start = offsets[node], end = offsets[node + 1];
    size_t co = (size_t)node * D64 + l8 * 8;
    float4 ta = *(const float4*)(sbuf + co);       // skip term, ch [8l8, 8l8+4)
    float4 tb = *(const float4*)(sbuf + co + 4);   //            ch [8l8+4, 8l8+8)

    if (end > start) {
        const float4 qa = *(const float4*)(q + co);
        const float4 qb = *(const float4*)(q + co + 4);
        float m = -3.0e38f, den = 0.f;
        float4 aa = make_float4(0.f, 0.f, 0.f, 0.f);
        float4 ab = make_float4(0.f, 0.f, 0.f, 0.f);

        int i = start + grp;
        int idx0 = (i < end) ? i : start;
        int sj0 = csr_src[idx0];
        const float* kp0 = kv + (size_t)sj0 * KVF;
        float4 ka = *(const float4*)(kp0 + l8 * 8);
        float4 kb = *(const float4*)(kp0 + l8 * 8 + 4);
        float4 vr = *(const float4*)(kp0 + 64 + l8 * 4);   // 8 bf16

        while (i < end) {
            int inext = i + 8;
            int idx1 = (inext < end) ? inext : start;
            int sj1 = csr_src[idx1];
            const float* kp1 = kv + (size_t)sj1 * KVF;
            float4 ka1 = *(const float4*)(kp1 + l8 * 8);
            float4 kb1 = *(const float4*)(kp1 + l8 * 8 + 4);
            float4 vr1 = *(const float4*)(kp1 + 64 + l8 * 4);

            float p = qa.x * ka.x + qa.y * ka.y + qa.z * ka.z + qa.w * ka.w
                    + qb.x * kb.x + qb.y * kb.y + qb.z * kb.z + qb.w * kb.w;
            p += __shfl_xor(p, 1, 8);
            p += __shfl_xor(p, 2, 8);
            p += __shfl_xor(p, 4, 8);
            p *= 0.125f;                       // 1/sqrt(64)
            float nm = fmaxf(m, p);
            float f  = __expf(m - nm);
            float e  = __expf(p - nm);
            den = den * f + e;
            // unpack 8 bf16 v channels from vr
            unsigned int u0 = __float_as_uint(vr.x), u1 = __float_as_uint(vr.y);
            unsigned int u2 = __float_as_uint(vr.z), u3 = __float_as_uint(vr.w);
            float v0 = __uint_as_float(u0 << 16), v1 = __uint_as_float(u0 & 0xFFFF0000u);
            float v2 = __uint_as_float(u1 << 16), v3 = __uint_as_float(u1 & 0xFFFF0000u);
            float v4 = __uint_as_float(u2 << 16), v5 = __uint_as_float(u2 & 0xFFFF0000u);
            float v6 = __uint_as_float(u3 << 16), v7 = __uint_as_float(u3 & 0xFFFF0000u);
            aa.x = aa.x * f + e * v0; aa.y = aa.y * f + e * v1;
            aa.z = aa.z * f + e * v2; aa.w = aa.w * f + e * v3;
            ab.x = ab.x * f + e * v4; ab.y = ab.y * f + e * v5;
            ab.z = ab.z * f + e * v6; ab.w = ab.w * f + e * v7;
            m = nm;
            ka = ka1; kb = kb1; vr = vr1;
            i = inext;
        }
        // butterfly merge of the 8 groups (inactive groups: den=0, exp->0)
        float M = fmaxf(m, __shfl_xor(m, 8));
        M = fmaxf(M, __shfl_xor(M, 16));
        M = fmaxf(M, __shfl_xor(M, 32));
        float f = __expf(m - M);
        float dd = den * f;
        dd += __shfl_xor(dd, 8); dd += __shfl_xor(dd, 16); dd += __shfl_xor(dd, 32);
        aa.x *= f; aa.y *= f; aa.z *= f; aa.w *= f;
        ab.x *= f; ab.y *= f; ab.z *= f; ab.w *= f;
        aa.x += __shfl_xor(aa.x, 8); aa.x += __shfl_xor(aa.x, 16); aa.x += __shfl_xor(aa.x, 32);
        aa.y += __shfl_xor(aa.y, 8); aa.y += __shfl_xor(aa.y, 16); aa.y += __shfl_xor(aa.y, 32);
        aa.z += __shfl_xor(aa.z, 8); aa.z += __shfl_xor(aa.z, 16); aa.z += __shfl_xor(aa.z, 32);
        aa.w += __shfl_xor(aa.w, 8); aa.w += __shfl_xor(aa.w, 16); aa.w += __shfl_xor(aa.w, 32);
        ab.x += __shfl_xor(ab.x, 8); ab.x += __shfl_xor(ab.x, 16); ab.x += __shfl_xor(ab.x, 32);
        ab.y += __shfl_xor(ab.y, 8); ab.y += __shfl_xor(ab.y, 16); ab.y += __shfl_xor(ab.y, 32);
        ab.z += __shfl_xor(ab.z, 8); ab.z += __shfl_xor(ab.z, 16); ab.z += __shfl_xor(ab.z, 32);
        ab.w += __shfl_xor(ab.w, 8); ab.w += __shfl_xor(ab.w, 16); ab.w += __shfl_xor(ab.w, 32);
        float inv = 1.f / dd;
        ta.x += aa.x * inv; ta.y += aa.y * inv; ta.z += aa.z * inv; ta.w += aa.w * inv;
        tb.x += ab.x * inv; tb.y += ab.y * inv; tb.z += ab.z * inv; tb.w += ab.w * inv;
    }
    if (MODE == 1) {
        ta.x = ta.x / (1.f + __expf(-ta.x)); ta.y = ta.y / (1.f + __expf(-ta.y));
        ta.z = ta.z / (1.f + __expf(-ta.z)); ta.w = ta.w / (1.f + __expf(-ta.w));
        tb.x = tb.x / (1.f + __expf(-tb.x)); tb.y = tb.y / (1.f + __expf(-tb.y));
        tb.z = tb.z / (1.f + __expf(-tb.z)); tb.w = tb.w / (1.f + __expf(-tb.w));
    } else if (MODE == 2) {
        const float4 xa = *(const float4*)(xin + co);
        const float4 xb = *(const float4*)(xin + co + 4);
        float u;
        u = ta.x + xa.x; ta.x = u / (1.f + __expf(-u));
        u = ta.y + xa.y; ta.y = u / (1.f + __expf(-u));
        u = ta.z + xa.z; ta.z = u / (1.f + __expf(-u));
        u = ta.w + xa.w; ta.w = u / (1.f + __expf(-u));
        u = tb.x + xb.x; tb.x = u / (1.f + __expf(-u));
        u = tb.y + xb.y; tb.y = u / (1.f + __expf(-u));
        u = tb.z + xb.z; tb.z = u / (1.f + __expf(-u));
        u = tb.w + xb.w; tb.w = u / (1.f + __expf(-u));
    } else {
        const float4 za = *(const float4*)(z + co);
        const float4 zb = *(const float4*)(z + co + 4);
        ta.x += 0.1f * za.x; ta.y += 0.1f * za.y;
        ta.z += 0.1f * za.z; ta.w += 0.1f * za.w;
        tb.x += 0.1f * zb.x; tb.y += 0.1f * zb.y;
        tb.z += 0.1f * zb.z; tb.w += 0.1f * zb.w;
    }
    if (grp == 0) {
        *(float4*)(out + co) = ta;
        *(float4*)(out + co + 4) = tb;
    }
}

// ---------------------------------------------------------------------------
extern "C" void kernel_launch(void* const* d_in, const int* in_sizes, int n_in,
                              void* d_out, int out_size, void* d_ws, size_t ws_size,
                              hipStream_t stream) {
    const float* x = (const float*)d_in[0];
    const int* ei  = (const int*)d_in[1];
    const float* z = (const float*)d_in[2];
    const float* W[3][4];
    const float* B[3][4];
    for (int l = 0; l < 3; ++l)
        for (int m = 0; m < 4; ++m) {
            W[l][m] = (const float*)d_in[3 + l * 8 + m * 2];
            B[l][m] = (const float*)d_in[3 + l * 8 + m * 2 + 1];
        }
    int N = in_sizes[0] / D64;
    int E = in_sizes[1] / 2;
    size_t ND = (size_t)N * D64;

    char* p = (char*)d_ws;
    auto alloc = [&](size_t bytes) {
        char* r = p;
        p += (bytes + 255) & ~(size_t)255;
        return r;
    };
    float* q       = (float*)alloc(ND * 4);
    float* kv      = (float*)alloc((size_t)N * KVF * 4);
    float* sb      = (float*)alloc(ND * 4);
    float* hA      = (float*)alloc(ND * 4);
    int* csr_src   = (int*)alloc((size_t)E * 4);
    int* dstc      = (int*)alloc((size_t)E * 4);
    int* srcc      = (int*)alloc((size_t)E * 4);
    int* offsets   = (int*)alloc((size_t)(N + 1) * 4);
    int* counts    = (int*)alloc((size_t)N * 4);
    int* nxt       = (int*)alloc((size_t)N * 4);
    int* partial   = (int*)alloc((size_t)N * 4);
    int* blockSums = (int*)alloc(4096);
    int* flag      = (int*)alloc(4);
    float* outp    = (float*)d_out;

    hipMemsetAsync(flag, 0, 4, stream);
    hipMemsetAsync(counts, 0, (size_t)N * 4, stream);
    int nchecks = E < 4096 ? E : 4096;
    detect_fmt<<<1, 256, 0, stream>>>(ei, nchecks, flag);
    hist_extract<<<(E + 255) / 256, 256, 0, stream>>>(ei, counts, dstc, srcc, E, flag);
    int nb = (N + 1023) / 1024;
    scan_blocks<<<nb, 256, 0, stream>>>(counts, partial, blockSums, N);
    scan_sums<<<1, 64, 0, stream>>>(blockSums, nb);
    scan_final<<<(N + 255) / 256, 256, 0, stream>>>(counts, partial, blockSums,
                                                    offsets, nxt, N);
    int npp = (N + NPART - 1) / NPART;
    scatter_part<<<NPART, 1024, npp * 4, stream>>>(dstc, srcc, nxt, csr_src, E, N);

    int gemm_grid = (N + 63) / 64;
    int node_grid = (N + 3) / 4;

    // layer 1: x -> hA, silu
    gemm_qkvs<<<gemm_grid, 256, 0, stream>>>(x, W[0][0], B[0][0], W[0][1], B[0][1],
                                             W[0][2], B[0][2], W[0][3], B[0][3],
                                             q, kv, sb, N);
    agg_fused<1><<<node_grid, 256, 0, stream>>>(q, kv, csr_src, offsets, sb,
                                                nullptr, nullptr, hA, N);
    // layer 2: hA -> hA (residual + silu)
    gemm_qkvs<<<gemm_grid, 256, 0, stream>>>(hA, W[1][0], B[1][0], W[1][1], B[1][1],
                                             W[1][2], B[1][2], W[1][3], B[1][3],
                                             q, kv, sb, N);
    agg_fused<2><<<node_grid, 256, 0, stream>>>(q, kv, csr_src, offsets, sb,
                                                hA, nullptr, hA, N);
    // layer 3: hA -> out, + 0.1*z
    gemm_qkvs<<<gemm_grid, 256, 0, stream>>>(hA, W[2][0], B[2][0], W[2][1], B[2][1],
                                             W[2][2], B[2][2], W[2][3], B[2][3],
                                             q, kv, sb, N);
    agg_fused<3><<<node_grid, 256, 0, stream>>>(q, kv, csr_src, offsets, sb,
                                                nullptr, z, outp, N);
}

// Round 8
// 308.554 us; speedup vs baseline: 2.1539x; 2.1539x over previous
//
#include <hip/hip_runtime.h>
#include <math.h>

// ---------------------------------------------------------------------------
// PseqStepV3: 3-layer TransformerConv (heads=1), N=50000, E=800000, D=64.
//   setup: detect edge dtype; build CSR by dst with an ATOMIC-FREE bucketed
//   pipeline (R7's 64-WG filter scatter was latency-bound at 346us; R6's
//   global-atomic scatter paid ~65us in cross-XCD atomic/line ping-pong):
//     bucket_hist (LDS hist, bucket=dst>>7) -> 3-kernel scan over
//     [bucket][block] -> bucket_scatter (LDS cursors, pairs bucket-sorted)
//     -> bucket_finalize (per-bucket local node hist + local scan -> offsets,
//        csr_src; all writes bucket-contiguous, all atomics in LDS)
//   per layer: fused q/kv/s GEMM (readlane broadcast, 16 rows/wave,
//              split-c 32KB LDS; k fp32 + v bf16 packed in one 384B row)
//              -> fused online-softmax aggregation (single-row kv gather)
// ---------------------------------------------------------------------------

#define D64 64
#define KVF 96       // floats per kv row: 64 fp32 k + 32 floats (64 bf16) v
#define NPB 128      // nodes per bucket (pow2 -> bucket = dst >> 7)
#define MAXNB 512    // LDS sizing bound for bucket count (N <= 65536)
#define CHUNK 4096   // edges per block in bucket passes

__device__ __forceinline__ unsigned short bf16_rne(float f) {
    unsigned int u = __float_as_uint(f);
    u += 0x7FFFu + ((u >> 16) & 1u);
    return (unsigned short)(u >> 16);
}

// ---- edge_index format detection: int64 rows have zero high words ----------
__global__ void detect_fmt(const int* __restrict__ ei, int nchecks, int* flag) {
    int t = blockIdx.x * blockDim.x + threadIdx.x;
    int acc = 0;
    for (int i = t; i < nchecks; i += blockDim.x * gridDim.x)
        acc |= ei[2 * i + 1];
    if (acc) atomicOr(flag, 1);   // nonzero => plain int32 layout
}

__device__ __forceinline__ int load_src(const int* ei, int e, int E, int is64) {
    return is64 ? ei[2 * e] : ei[e];
}
__device__ __forceinline__ int load_dst(const int* ei, int e, int E, int is64) {
    return is64 ? ei[2 * E + 2 * e] : ei[E + e];
}

// ---- CSR build: bucketed, atomic-free (LDS atomics only) -------------------
// P1: per-block LDS histogram over buckets; write transposed bhT[bkt][blk]
__global__ void bucket_hist(const int* __restrict__ ei, int* __restrict__ bhT,
                            int E, int nblk, int NB, const int* __restrict__ flag) {
    __shared__ int h[MAXNB];
    int blk = blockIdx.x, tid = threadIdx.x;
    for (int i = tid; i < NB; i += 256) h[i] = 0;
    __syncthreads();
    int is64 = (*flag == 0);
    int e1 = blk * CHUNK + CHUNK; if (e1 > E) e1 = E;
    for (int e = blk * CHUNK + tid; e < e1; e += 256)
        atomicAdd(&h[load_dst(ei, e, E, is64) >> 7], 1);
    __syncthreads();
    for (int i = tid; i < NB; i += 256) bhT[i * nblk + blk] = h[i];
}

// P2: generic multi-block scan (inclusive partials + block sums)
__global__ void scan_blocks(const int* __restrict__ counts, int* __restrict__ partial,
                            int* __restrict__ blockSums, int n) {
    int tid = threadIdx.x;                 // 256
    int base = blockIdx.x * 1024 + tid * 4;
    int4 c = make_int4(0, 0, 0, 0);
    if (base + 3 < n) c = *(const int4*)&counts[base];
    else {
        if (base + 0 < n) c.x = counts[base + 0];
        if (base + 1 < n) c.y = counts[base + 1];
        if (base + 2 < n) c.z = counts[base + 2];
        if (base + 3 < n) c.w = counts[base + 3];
    }
    int s1 = c.x, s2 = s1 + c.y, s3 = s2 + c.z, s4 = s3 + c.w;
    int lane = tid & 63, wave = tid >> 6;
    int v = s4;
#pragma unroll
    for (int off = 1; off < 64; off <<= 1) {
        int t = __shfl_up(v, off);
        if (lane >= off) v += t;
    }
    __shared__ int wsum[4];
    if (lane == 63) wsum[wave] = v;
    __syncthreads();
    int wpre = 0;
    for (int w = 0; w < wave; ++w) wpre += wsum[w];
    int pre = wpre + v - s4;
    if (base + 0 < n) partial[base + 0] = pre + s1;
    if (base + 1 < n) partial[base + 1] = pre + s2;
    if (base + 2 < n) partial[base + 2] = pre + s3;
    if (base + 3 < n) partial[base + 3] = pre + s4;
    if (tid == 255) blockSums[blockIdx.x] = wsum[0] + wsum[1] + wsum[2] + wsum[3];
}

__global__ void scan_sums(int* __restrict__ bs, int nb) {
    int lane = threadIdx.x;                // 64
    int carry = 0;
    for (int b0 = 0; b0 < nb; b0 += 64) {
        int i = b0 + lane;
        int val = (i < nb) ? bs[i] : 0;
        int v = val;
#pragma unroll
        for (int off = 1; off < 64; off <<= 1) {
            int t = __shfl_up(v, off);
            if (lane >= off) v += t;
        }
        if (i < nb) bs[i] = carry + v - val;   // exclusive
        carry += __shfl(v, 63);
    }
}

__global__ void make_excl(const int* __restrict__ bh, const int* __restrict__ partial,
                          const int* __restrict__ bs, int* __restrict__ ebase, int n) {
    int i = blockIdx.x * 256 + threadIdx.x;
    if (i >= n) return;
    ebase[i] = partial[i] + bs[i >> 10] - bh[i];   // exclusive global scan
}

// P3: replay chunk; LDS cursors (seeded from ebase) -> pairs bucket-sorted
__global__ void bucket_scatter(const int* __restrict__ ei, const int* __restrict__ ebase,
                               int2* __restrict__ pairs, int E, int nblk, int NB,
                               const int* __restrict__ flag) {
    __shared__ int cur[MAXNB];
    int blk = blockIdx.x, tid = threadIdx.x;
    for (int i = tid; i < NB; i += 256) cur[i] = ebase[i * nblk + blk];
    __syncthreads();
    int is64 = (*flag == 0);
    int e1 = blk * CHUNK + CHUNK; if (e1 > E) e1 = E;
    for (int e = blk * CHUNK + tid; e < e1; e += 256) {
        int s = load_src(ei, e, E, is64);
        int d = load_dst(ei, e, E, is64);
        int pos = atomicAdd(&cur[d >> 7], 1);
        pairs[pos] = make_int2(s, d);
    }
}

// P4: one WG per bucket: local node hist -> local scan -> offsets + csr_src.
// All reads/writes land in the bucket's contiguous slice; atomics in LDS.
__global__ void bucket_finalize(const int2* __restrict__ pairs,
                                const int* __restrict__ ebase, int nblk, int NB,
                                int* __restrict__ csr_src, int* __restrict__ offsets,
                                int N, int E) {
    __shared__ int hist[NPB];
    __shared__ int cur[NPB];
    int b = blockIdx.x, tid = threadIdx.x;
    int n0 = b * NPB;
    int cnt = N - n0; if (cnt > NPB) cnt = NPB;
    if (cnt <= 0) return;
    int estart = ebase[b * nblk];
    int eend = (b + 1 < NB) ? ebase[(b + 1) * nblk] : E;
    for (int i = tid; i < cnt; i += 256) hist[i] = 0;
    __syncthreads();
    for (int e = estart + tid; e < eend; e += 256)
        atomicAdd(&hist[pairs[e].y - n0], 1);
    __syncthreads();
    if (tid == 0) {
        int run = estart;
        for (int i = 0; i < cnt; ++i) {
            cur[i] = run;
            offsets[n0 + i] = run;
            run += hist[i];
        }
    }
    if (b == 0 && tid == 1) offsets[N] = E;
    __syncthreads();
    for (int e = estart + tid; e < eend; e += 256) {
        int2 pr = pairs[e];
        int pos = atomicAdd(&cur[pr.y - n0], 1);
        csr_src[pos] = pr.x;
    }
}

// ---- fused q/kv/s GEMM -----------------------------------------------------
// Wave: 16 rows x 4 matrices. x broadcast via readlane (SGPR path); weight
// quad via one ds_read_b128 per c-step (1 LDS op / 64 FMAs). c-loop split in
// two 32-channel halves so LDS = 32 KiB. Outputs: q fp32, s fp32, and a packed
// kv row per node: 64 fp32 k + 64 bf16 v = 384 B contiguous (one-gather agg).
__launch_bounds__(256)
__global__ void gemm_qkvs(const float* __restrict__ x,
                          const float* __restrict__ Wq, const float* __restrict__ bq,
                          const float* __restrict__ Wk, const float* __restrict__ bk,
                          const float* __restrict__ Wv, const float* __restrict__ bv,
                          const float* __restrict__ Ws, const float* __restrict__ bs,
                          float* __restrict__ q, float* __restrict__ kv,
                          float* __restrict__ s, int n) {
    __shared__ float Wh[32 * 256];  // 32 KiB: Wh[c][lane][4] for one c-half
    int tid = threadIdx.x;
    int wave = tid >> 6, lane = tid & 63;
    int row0 = blockIdx.x * 64 + wave * 16;

    float xr[16];
#pragma unroll
    for (int j = 0; j < 16; ++j)
        xr[j] = (row0 + j < n) ? x[(size_t)(row0 + j) * D64 + lane] : 0.f;

    float bqv = bq[lane], bkv = bk[lane], bvv = bv[lane], bsv = bs[lane];
    float aq[16], ak[16], av[16], as_[16];
#pragma unroll
    for (int j = 0; j < 16; ++j) { aq[j] = bqv; ak[j] = bkv; av[j] = bvv; as_[j] = bsv; }

    for (int half = 0; half < 2; ++half) {
        int c0 = half * 32;
        for (int i = tid; i < 32 * 64; i += 256) {
            int c = i >> 6, l = i & 63;
            int gi = (c0 + c) * 64 + l;
            float4 wv4;
            wv4.x = Wq[gi]; wv4.y = Wk[gi]; wv4.z = Wv[gi]; wv4.w = Ws[gi];
            *(float4*)&Wh[c * 256 + l * 4] = wv4;
        }
        __syncthreads();
#pragma unroll 4
        for (int cc = 0; cc < 32; ++cc) {
            int c = c0 + cc;
            const float4 w = *(const float4*)&Wh[cc * 256 + lane * 4];
#pragma unroll
            for (int j = 0; j < 16; ++j) {
                float xs = __int_as_float(
                    __builtin_amdgcn_readlane(__float_as_int(xr[j]), c));
                aq[j] += xs * w.x;
                ak[j] += xs * w.y;
                av[j] += xs * w.z;
                as_[j] += xs * w.w;
            }
        }
        __syncthreads();
    }
#pragma unroll
    for (int j = 0; j < 16; ++j) {
        if (row0 + j < n) {
            size_t o = (size_t)(row0 + j) * D64 + lane;
            q[o] = aq[j]; s[o] = as_[j];
            size_t rb = (size_t)(row0 + j) * KVF;
            kv[rb + lane] = ak[j];                         // k fp32, 256B row
            unsigned short* vp = (unsigned short*)(kv + rb + 64);
            vp[lane] = bf16_rne(av[j]);                    // v bf16, 128B row
        }
    }
}

// ---- fused edge-score + online-softmax aggregation + epilogue --------------
// Wave = 1 node. 8 groups x 8 lanes; group owns one edge/iter, lane l8 owns
// channels [8*l8, 8*l8+8). Per edge one contiguous 384B kv-row gather:
// 2x float4 k (fp32) + 1x float4 = 8x bf16 v. 2-deep load pipeline. Online
// (m, den, acc) per group; butterfly-merged over xor 8/16/32.
// MODE 1: out = silu(t)   MODE 2: out = silu(t + xin)   MODE 3: out = t + 0.1*z
template <int MODE>
__launch_bounds__(256)
__global__ void agg_fused(const float* __restrict__ q, const float* __restrict__ kv,
                          const int* __restrict__ csr_src,
                          const int* __restrict__ offsets,
                          const float* __restrict__ sbuf, const float* __restrict__ xin,
                          const float* __restrict__ z, float* __restrict__ out, int n) {
    int node = blockIdx.x * 4 + (threadIdx.x >> 6);
    if (node >= n) return;
    int lane = threadIdx.x & 63;
    int grp = lane >> 3, l8 = lane & 7;
    int start = offsets[node], end = offsets[node + 1];
    size_t co = (size_t)node * D64 + l8 * 8;
    float4 ta = *(const float4*)(sbuf + co);       // skip term, ch [8l8, 8l8+4)
    float4 tb = *(const float4*)(sbuf + co + 4);   //            ch [8l8+4, 8l8+8)

    if (end > start) {
        const float4 qa = *(const float4*)(q + co);
        const float4 qb = *(const float4*)(q + co + 4);
        float m = -3.0e38f, den = 0.f;
        float4 aa = make_float4(0.f, 0.f, 0.f, 0.f);
        float4 ab = make_float4(0.f, 0.f, 0.f, 0.f);

        int i = start + grp;
        int idx0 = (i < end) ? i : start;
        int sj0 = csr_src[idx0];
        const float* kp0 = kv + (size_t)sj0 * KVF;
        float4 ka = *(const float4*)(kp0 + l8 * 8);
        float4 kb = *(const float4*)(kp0 + l8 * 8 + 4);
        float4 vr = *(const float4*)(kp0 + 64 + l8 * 4);   // 8 bf16

        while (i < end) {
            int inext = i + 8;
            int idx1 = (inext < end) ? inext : start;
            int sj1 = csr_src[idx1];
            const float* kp1 = kv + (size_t)sj1 * KVF;
            float4 ka1 = *(const float4*)(kp1 + l8 * 8);
            float4 kb1 = *(const float4*)(kp1 + l8 * 8 + 4);
            float4 vr1 = *(const float4*)(kp1 + 64 + l8 * 4);

            float p = qa.x * ka.x + qa.y * ka.y + qa.z * ka.z + qa.w * ka.w
                    + qb.x * kb.x + qb.y * kb.y + qb.z * kb.z + qb.w * kb.w;
            p += __shfl_xor(p, 1, 8);
            p += __shfl_xor(p, 2, 8);
            p += __shfl_xor(p, 4, 8);
            p *= 0.125f;                       // 1/sqrt(64)
            float nm = fmaxf(m, p);
            float f  = __expf(m - nm);
            float e  = __expf(p - nm);
            den = den * f + e;
            // unpack 8 bf16 v channels from vr
            unsigned int u0 = __float_as_uint(vr.x), u1 = __float_as_uint(vr.y);
            unsigned int u2 = __float_as_uint(vr.z), u3 = __float_as_uint(vr.w);
            float v0 = __uint_as_float(u0 << 16), v1 = __uint_as_float(u0 & 0xFFFF0000u);
            float v2 = __uint_as_float(u1 << 16), v3 = __uint_as_float(u1 & 0xFFFF0000u);
            float v4 = __uint_as_float(u2 << 16), v5 = __uint_as_float(u2 & 0xFFFF0000u);
            float v6 = __uint_as_float(u3 << 16), v7 = __uint_as_float(u3 & 0xFFFF0000u);
            aa.x = aa.x * f + e * v0; aa.y = aa.y * f + e * v1;
            aa.z = aa.z * f + e * v2; aa.w = aa.w * f + e * v3;
            ab.x = ab.x * f + e * v4; ab.y = ab.y * f + e * v5;
            ab.z = ab.z * f + e * v6; ab.w = ab.w * f + e * v7;
            m = nm;
            ka = ka1; kb = kb1; vr = vr1;
            i = inext;
        }
        // butterfly merge of the 8 groups (inactive groups: den=0, exp->0)
        float M = fmaxf(m, __shfl_xor(m, 8));
        M = fmaxf(M, __shfl_xor(M, 16));
        M = fmaxf(M, __shfl_xor(M, 32));
        float f = __expf(m - M);
        float dd = den * f;
        dd += __shfl_xor(dd, 8); dd += __shfl_xor(dd, 16); dd += __shfl_xor(dd, 32);
        aa.x *= f; aa.y *= f; aa.z *= f; aa.w *= f;
        ab.x *= f; ab.y *= f; ab.z *= f; ab.w *= f;
        aa.x += __shfl_xor(aa.x, 8); aa.x += __shfl_xor(aa.x, 16); aa.x += __shfl_xor(aa.x, 32);
        aa.y += __shfl_xor(aa.y, 8); aa.y += __shfl_xor(aa.y, 16); aa.y += __shfl_xor(aa.y, 32);
        aa.z += __shfl_xor(aa.z, 8); aa.z += __shfl_xor(aa.z, 16); aa.z += __shfl_xor(aa.z, 32);
        aa.w += __shfl_xor(aa.w, 8); aa.w += __shfl_xor(aa.w, 16); aa.w += __shfl_xor(aa.w, 32);
        ab.x += __shfl_xor(ab.x, 8); ab.x += __shfl_xor(ab.x, 16); ab.x += __shfl_xor(ab.x, 32);
        ab.y += __shfl_xor(ab.y, 8); ab.y += __shfl_xor(ab.y, 16); ab.y += __shfl_xor(ab.y, 32);
        ab.z += __shfl_xor(ab.z, 8); ab.z += __shfl_xor(ab.z, 16); ab.z += __shfl_xor(ab.z, 32);
        ab.w += __shfl_xor(ab.w, 8); ab.w += __shfl_xor(ab.w, 16); ab.w += __shfl_xor(ab.w, 32);
        float inv = 1.f / dd;
        ta.x += aa.x * inv; ta.y += aa.y * inv; ta.z += aa.z * inv; ta.w += aa.w * inv;
        tb.x += ab.x * inv; tb.y += ab.y * inv; tb.z += ab.z * inv; tb.w += ab.w * inv;
    }
    if (MODE == 1) {
        ta.x = ta.x / (1.f + __expf(-ta.x)); ta.y = ta.y / (1.f + __expf(-ta.y));
        ta.z = ta.z / (1.f + __expf(-ta.z)); ta.w = ta.w / (1.f + __expf(-ta.w));
        tb.x = tb.x / (1.f + __expf(-tb.x)); tb.y = tb.y / (1.f + __expf(-tb.y));
        tb.z = tb.z / (1.f + __expf(-tb.z)); tb.w = tb.w / (1.f + __expf(-tb.w));
    } else if (MODE == 2) {
        const float4 xa = *(const float4*)(xin + co);
        const float4 xb = *(const float4*)(xin + co + 4);
        float u;
        u = ta.x + xa.x; ta.x = u / (1.f + __expf(-u));
        u = ta.y + xa.y; ta.y = u / (1.f + __expf(-u));
        u = ta.z + xa.z; ta.z = u / (1.f + __expf(-u));
        u = ta.w + xa.w; ta.w = u / (1.f + __expf(-u));
        u = tb.x + xb.x; tb.x = u / (1.f + __expf(-u));
        u = tb.y + xb.y; tb.y = u / (1.f + __expf(-u));
        u = tb.z + xb.z; tb.z = u / (1.f + __expf(-u));
        u = tb.w + xb.w; tb.w = u / (1.f + __expf(-u));
    } else {
        const float4 za = *(const float4*)(z + co);
        const float4 zb = *(const float4*)(z + co + 4);
        ta.x += 0.1f * za.x; ta.y += 0.1f * za.y;
        ta.z += 0.1f * za.z; ta.w += 0.1f * za.w;
        tb.x += 0.1f * zb.x; tb.y += 0.1f * zb.y;
        tb.z += 0.1f * zb.z; tb.w += 0.1f * zb.w;
    }
    if (grp == 0) {
        *(float4*)(out + co) = ta;
        *(float4*)(out + co + 4) = tb;
    }
}

// ---------------------------------------------------------------------------
extern "C" void kernel_launch(void* const* d_in, const int* in_sizes, int n_in,
                              void* d_out, int out_size, void* d_ws, size_t ws_size,
                              hipStream_t stream) {
    const float* x = (const float*)d_in[0];
    const int* ei  = (const int*)d_in[1];
    const float* z = (const float*)d_in[2];
    const float* W[3][4];
    const float* B[3][4];
    for (int l = 0; l < 3; ++l)
        for (int m = 0; m < 4; ++m) {
            W[l][m] = (const float*)d_in[3 + l * 8 + m * 2];
            B[l][m] = (const float*)d_in[3 + l * 8 + m * 2 + 1];
        }
    int N = in_sizes[0] / D64;
    int E = in_sizes[1] / 2;
    size_t ND = (size_t)N * D64;

    int NB   = (N + NPB - 1) / NPB;          // buckets (391)
    int nblk = (E + CHUNK - 1) / CHUNK;      // edge chunks (196)
    int nscan = NB * nblk;                   // ~77k
    int nb2  = (nscan + 1023) / 1024;        // scan blocks (~75)

    char* p = (char*)d_ws;
    auto alloc = [&](size_t bytes) {
        char* r = p;
        p += (bytes + 255) & ~(size_t)255;
        return r;
    };
    float* q       = (float*)alloc(ND * 4);
    float* kv      = (float*)alloc((size_t)N * KVF * 4);
    float* sb      = (float*)alloc(ND * 4);
    float* hA      = (float*)alloc(ND * 4);
    int* csr_src   = (int*)alloc((size_t)E * 4);
    int2* pairs    = (int2*)alloc((size_t)E * 8);
    int* offsets   = (int*)alloc((size_t)(N + 1) * 4);
    int* bhT       = (int*)alloc((size_t)nscan * 4);
    int* partial   = (int*)alloc((size_t)nscan * 4);
    int* ebase     = (int*)alloc((size_t)nscan * 4);
    int* blockSums = (int*)alloc((size_t)nb2 * 4);
    int* flag      = (int*)alloc(4);
    float* outp    = (float*)d_out;

    hipMemsetAsync(flag, 0, 4, stream);
    int nchecks = E < 4096 ? E : 4096;
    detect_fmt<<<1, 256, 0, stream>>>(ei, nchecks, flag);
    bucket_hist<<<nblk, 256, 0, stream>>>(ei, bhT, E, nblk, NB, flag);
    scan_blocks<<<nb2, 256, 0, stream>>>(bhT, partial, blockSums, nscan);
    scan_sums<<<1, 64, 0, stream>>>(blockSums, nb2);
    make_excl<<<(nscan + 255) / 256, 256, 0, stream>>>(bhT, partial, blockSums,
                                                       ebase, nscan);
    bucket_scatter<<<nblk, 256, 0, stream>>>(ei, ebase, pairs, E, nblk, NB, flag);
    bucket_finalize<<<NB, 256, 0, stream>>>(pairs, ebase, nblk, NB,
                                            csr_src, offsets, N, E);

    int gemm_grid = (N + 63) / 64;
    int node_grid = (N + 3) / 4;

    // layer 1: x -> hA, silu
    gemm_qkvs<<<gemm_grid, 256, 0, stream>>>(x, W[0][0], B[0][0], W[0][1], B[0][1],
                                             W[0][2], B[0][2], W[0][3], B[0][3],
                                             q, kv, sb, N);
    agg_fused<1><<<node_grid, 256, 0, stream>>>(q, kv, csr_src, offsets, sb,
                                                nullptr, nullptr, hA, N);
    // layer 2: hA -> hA (residual + silu)
    gemm_qkvs<<<gemm_grid, 256, 0, stream>>>(hA, W[1][0], B[1][0], W[1][1], B[1][1],
                                             W[1][2], B[1][2], W[1][3], B[1][3],
                                             q, kv, sb, N);
    agg_fused<2><<<node_grid, 256, 0, stream>>>(q, kv, csr_src, offsets, sb,
                                                hA, nullptr, hA, N);
    // layer 3: hA -> out, + 0.1*z
    gemm_qkvs<<<gemm_grid, 256, 0, stream>>>(hA, W[2][0], B[2][0], W[2][1], B[2][1],
                                             W[2][2], B[2][2], W[2][3], B[2][3],
                                             q, kv, sb, N);
    agg_fused<3><<<node_grid, 256, 0, stream>>>(q, kv, csr_src, offsets, sb,
                                                nullptr, z, outp, N);
}

// Round 9
// 290.766 us; speedup vs baseline: 2.2857x; 1.0612x over previous
//
#include <hip/hip_runtime.h>
#include <math.h>

// ---------------------------------------------------------------------------
// PseqStepV3: 3-layer TransformerConv (heads=1), N=50000, E=800000, D=64.
//   setup: detect edge dtype; atomic-free bucketed CSR build (R8, ~25us).
//   per layer: fused q/kv/s GEMM (readlane broadcast, 16 rows/wave, split-c
//              32KB LDS; k fp16 + v bf16 packed in one 256B row)
//              -> fused online-softmax aggregation (single 256B-row gather,
//                 fdot2 fp16 dot for scores)
// ---------------------------------------------------------------------------

#define D64 64
#define KVF 64       // floats per kv row: 32 words fp16 k + 32 words bf16 v
#define NPB 128      // nodes per bucket (pow2 -> bucket = dst >> 7)
#define MAXNB 512    // LDS sizing bound for bucket count (N <= 65536)
#define CHUNK 4096   // edges per block in bucket passes

typedef _Float16 h2 __attribute__((ext_vector_type(2)));

__device__ __forceinline__ unsigned short bf16_rne(float f) {
    unsigned int u = __float_as_uint(f);
    u += 0x7FFFu + ((u >> 16) & 1u);
    return (unsigned short)(u >> 16);
}

// ---- edge_index format detection: int64 rows have zero high words ----------
__global__ void detect_fmt(const int* __restrict__ ei, int nchecks, int* flag) {
    int t = blockIdx.x * blockDim.x + threadIdx.x;
    int acc = 0;
    for (int i = t; i < nchecks; i += blockDim.x * gridDim.x)
        acc |= ei[2 * i + 1];
    if (acc) atomicOr(flag, 1);   // nonzero => plain int32 layout
}

__device__ __forceinline__ int load_src(const int* ei, int e, int E, int is64) {
    return is64 ? ei[2 * e] : ei[e];
}
__device__ __forceinline__ int load_dst(const int* ei, int e, int E, int is64) {
    return is64 ? ei[2 * E + 2 * e] : ei[E + e];
}

// ---- CSR build: bucketed, atomic-free (LDS atomics only) -------------------
__global__ void bucket_hist(const int* __restrict__ ei, int* __restrict__ bhT,
                            int E, int nblk, int NB, const int* __restrict__ flag) {
    __shared__ int h[MAXNB];
    int blk = blockIdx.x, tid = threadIdx.x;
    for (int i = tid; i < NB; i += 256) h[i] = 0;
    __syncthreads();
    int is64 = (*flag == 0);
    int e1 = blk * CHUNK + CHUNK; if (e1 > E) e1 = E;
    for (int e = blk * CHUNK + tid; e < e1; e += 256)
        atomicAdd(&h[load_dst(ei, e, E, is64) >> 7], 1);
    __syncthreads();
    for (int i = tid; i < NB; i += 256) bhT[i * nblk + blk] = h[i];
}

__global__ void scan_blocks(const int* __restrict__ counts, int* __restrict__ partial,
                            int* __restrict__ blockSums, int n) {
    int tid = threadIdx.x;                 // 256
    int base = blockIdx.x * 1024 + tid * 4;
    int4 c = make_int4(0, 0, 0, 0);
    if (base + 3 < n) c = *(const int4*)&counts[base];
    else {
        if (base + 0 < n) c.x = counts[base + 0];
        if (base + 1 < n) c.y = counts[base + 1];
        if (base + 2 < n) c.z = counts[base + 2];
        if (base + 3 < n) c.w = counts[base + 3];
    }
    int s1 = c.x, s2 = s1 + c.y, s3 = s2 + c.z, s4 = s3 + c.w;
    int lane = tid & 63, wave = tid >> 6;
    int v = s4;
#pragma unroll
    for (int off = 1; off < 64; off <<= 1) {
        int t = __shfl_up(v, off);
        if (lane >= off) v += t;
    }
    __shared__ int wsum[4];
    if (lane == 63) wsum[wave] = v;
    __syncthreads();
    int wpre = 0;
    for (int w = 0; w < wave; ++w) wpre += wsum[w];
    int pre = wpre + v - s4;
    if (base + 0 < n) partial[base + 0] = pre + s1;
    if (base + 1 < n) partial[base + 1] = pre + s2;
    if (base + 2 < n) partial[base + 2] = pre + s3;
    if (base + 3 < n) partial[base + 3] = pre + s4;
    if (tid == 255) blockSums[blockIdx.x] = wsum[0] + wsum[1] + wsum[2] + wsum[3];
}

__global__ void scan_sums(int* __restrict__ bs, int nb) {
    int lane = threadIdx.x;                // 64
    int carry = 0;
    for (int b0 = 0; b0 < nb; b0 += 64) {
        int i = b0 + lane;
        int val = (i < nb) ? bs[i] : 0;
        int v = val;
#pragma unroll
        for (int off = 1; off < 64; off <<= 1) {
            int t = __shfl_up(v, off);
            if (lane >= off) v += t;
        }
        if (i < nb) bs[i] = carry + v - val;   // exclusive
        carry += __shfl(v, 63);
    }
}

__global__ void make_excl(const int* __restrict__ bh, const int* __restrict__ partial,
                          const int* __restrict__ bs, int* __restrict__ ebase, int n) {
    int i = blockIdx.x * 256 + threadIdx.x;
    if (i >= n) return;
    ebase[i] = partial[i] + bs[i >> 10] - bh[i];   // exclusive global scan
}

__global__ void bucket_scatter(const int* __restrict__ ei, const int* __restrict__ ebase,
                               int2* __restrict__ pairs, int E, int nblk, int NB,
                               const int* __restrict__ flag) {
    __shared__ int cur[MAXNB];
    int blk = blockIdx.x, tid = threadIdx.x;
    for (int i = tid; i < NB; i += 256) cur[i] = ebase[i * nblk + blk];
    __syncthreads();
    int is64 = (*flag == 0);
    int e1 = blk * CHUNK + CHUNK; if (e1 > E) e1 = E;
    for (int e = blk * CHUNK + tid; e < e1; e += 256) {
        int s = load_src(ei, e, E, is64);
        int d = load_dst(ei, e, E, is64);
        int pos = atomicAdd(&cur[d >> 7], 1);
        pairs[pos] = make_int2(s, d);
    }
}

__global__ void bucket_finalize(const int2* __restrict__ pairs,
                                const int* __restrict__ ebase, int nblk, int NB,
                                int* __restrict__ csr_src, int* __restrict__ offsets,
                                int N, int E) {
    __shared__ int hist[NPB];
    __shared__ int cur[NPB];
    int b = blockIdx.x, tid = threadIdx.x;
    int n0 = b * NPB;
    int cnt = N - n0; if (cnt > NPB) cnt = NPB;
    if (cnt <= 0) return;
    int estart = ebase[b * nblk];
    int eend = (b + 1 < NB) ? ebase[(b + 1) * nblk] : E;
    for (int i = tid; i < cnt; i += 256) hist[i] = 0;
    __syncthreads();
    for (int e = estart + tid; e < eend; e += 256)
        atomicAdd(&hist[pairs[e].y - n0], 1);
    __syncthreads();
    if (tid == 0) {
        int run = estart;
        for (int i = 0; i < cnt; ++i) {
            cur[i] = run;
            offsets[n0 + i] = run;
            run += hist[i];
        }
    }
    if (b == 0 && tid == 1) offsets[N] = E;
    __syncthreads();
    for (int e = estart + tid; e < eend; e += 256) {
        int2 pr = pairs[e];
        int pos = atomicAdd(&cur[pr.y - n0], 1);
        csr_src[pos] = pr.x;
    }
}

// ---- fused q/kv/s GEMM -----------------------------------------------------
// Wave: 16 rows x 4 matrices. x broadcast via readlane; weight quad via one
// ds_read_b128 per c-step. Outputs: q fp32, s fp32, and a packed kv row per
// node: 32 words fp16 k + 32 words bf16 v = 256 B contiguous.
__launch_bounds__(256)
__global__ void gemm_qkvs(const float* __restrict__ x,
                          const float* __restrict__ Wq, const float* __restrict__ bq,
                          const float* __restrict__ Wk, const float* __restrict__ bk,
                          const float* __restrict__ Wv, const float* __restrict__ bv,
                          const float* __restrict__ Ws, const float* __restrict__ bs,
                          float* __restrict__ q, float* __restrict__ kv,
                          float* __restrict__ s, int n) {
    __shared__ float Wh[32 * 256];  // 32 KiB: Wh[c][lane][4] for one c-half
    int tid = threadIdx.x;
    int wave = tid >> 6, lane = tid & 63;
    int row0 = blockIdx.x * 64 + wave * 16;

    float xr[16];
#pragma unroll
    for (int j = 0; j < 16; ++j)
        xr[j] = (row0 + j < n) ? x[(size_t)(row0 + j) * D64 + lane] : 0.f;

    float bqv = bq[lane], bkv = bk[lane], bvv = bv[lane], bsv = bs[lane];
    float aq[16], ak[16], av[16], as_[16];
#pragma unroll
    for (int j = 0; j < 16; ++j) { aq[j] = bqv; ak[j] = bkv; av[j] = bvv; as_[j] = bsv; }

    for (int half = 0; half < 2; ++half) {
        int c0 = half * 32;
        for (int i = tid; i < 32 * 64; i += 256) {
            int c = i >> 6, l = i & 63;
            int gi = (c0 + c) * 64 + l;
            float4 wv4;
            wv4.x = Wq[gi]; wv4.y = Wk[gi]; wv4.z = Wv[gi]; wv4.w = Ws[gi];
            *(float4*)&Wh[c * 256 + l * 4] = wv4;
        }
        __syncthreads();
#pragma unroll 4
        for (int cc = 0; cc < 32; ++cc) {
            int c = c0 + cc;
            const float4 w = *(const float4*)&Wh[cc * 256 + lane * 4];
#pragma unroll
            for (int j = 0; j < 16; ++j) {
                float xs = __int_as_float(
                    __builtin_amdgcn_readlane(__float_as_int(xr[j]), c));
                aq[j] += xs * w.x;
                ak[j] += xs * w.y;
                av[j] += xs * w.z;
                as_[j] += xs * w.w;
            }
        }
        __syncthreads();
    }
#pragma unroll
    for (int j = 0; j < 16; ++j) {
        if (row0 + j < n) {
            size_t o = (size_t)(row0 + j) * D64 + lane;
            q[o] = aq[j]; s[o] = as_[j];
            // pack kv row: channel pairs (2p, 2p+1) -> 32-bit words
            unsigned int khu = (unsigned int)__builtin_bit_cast(
                unsigned short, (_Float16)ak[j]);
            unsigned int khn = (unsigned int)__shfl_xor((int)khu, 1);
            unsigned int kword = (lane & 1) ? ((khu << 16) | khn)
                                            : (khu | (khn << 16));
            int kgot = __shfl((int)kword, (lane & 31) * 2);
            unsigned int vbu = (unsigned int)bf16_rne(av[j]);
            unsigned int vbn = (unsigned int)__shfl_xor((int)vbu, 1);
            unsigned int vword = (lane & 1) ? ((vbu << 16) | vbn)
                                            : (vbu | (vbn << 16));
            int vgot = __shfl((int)vword, (lane & 31) * 2);
            unsigned int* row = (unsigned int*)(kv + (size_t)(row0 + j) * KVF);
            if (lane < 32) row[lane] = (unsigned int)kgot;          // k fp16
            else           row[32 + (lane - 32)] = (unsigned int)vgot; // v bf16
        }
    }
}

// ---- fused edge-score + online-softmax aggregation + epilogue --------------
// Wave = 1 node. 8 groups x 8 lanes; group owns one edge/iter, lane l8 owns
// channels [8*l8, 8*l8+8). Per edge one contiguous 256B kv-row gather:
// 1x float4 of fp16 k (fdot2 vs fp16 q) + 1x float4 of bf16 v. 2-deep load
// pipeline. Online (m, den, acc) per group; butterfly-merged over xor 8/16/32.
// MODE 1: out = silu(t)   MODE 2: out = silu(t + xin)   MODE 3: out = t + 0.1*z
template <int MODE>
__launch_bounds__(256)
__global__ void agg_fused(const float* __restrict__ q, const float* __restrict__ kv,
                          const int* __restrict__ csr_src,
                          const int* __restrict__ offsets,
                          const float* __restrict__ sbuf, const float* __restrict__ xin,
                          const float* __restrict__ z, float* __restrict__ out, int n) {
    int node = blockIdx.x * 4 + (threadIdx.x >> 6);
    if (node >= n) return;
    int lane = threadIdx.x & 63;
    int grp = lane >> 3, l8 = lane & 7;
    int start = offsets[node], end = offsets[node + 1];
    size_t co = (size_t)node * D64 + l8 * 8;
    float4 ta = *(const float4*)(sbuf + co);       // skip term, ch [8l8, 8l8+4)
    float4 tb = *(const float4*)(sbuf + co + 4);   //            ch [8l8+4, 8l8+8)

    if (end > start) {
        const float4 qa = *(const float4*)(q + co);
        const float4 qb = *(const float4*)(q + co + 4);
        h2 hq0, hq1, hq2, hq3;
        hq0[0] = (_Float16)qa.x; hq0[1] = (_Float16)qa.y;
        hq1[0] = (_Float16)qa.z; hq1[1] = (_Float16)qa.w;
        hq2[0] = (_Float16)qb.x; hq2[1] = (_Float16)qb.y;
        hq3[0] = (_Float16)qb.z; hq3[1] = (_Float16)qb.w;
        float m = -3.0e38f, den = 0.f;
        float4 aa = make_float4(0.f, 0.f, 0.f, 0.f);
        float4 ab = make_float4(0.f, 0.f, 0.f, 0.f);

        int i = start + grp;
        int idx0 = (i < end) ? i : start;
        int sj0 = csr_src[idx0];
        const float* kp0 = kv + (size_t)sj0 * KVF;
        float4 kw = *(const float4*)(kp0 + l8 * 4);        // 8 fp16 k
        float4 vw = *(const float4*)(kp0 + 32 + l8 * 4);   // 8 bf16 v

        while (i < end) {
            int inext = i + 8;
            int idx1 = (inext < end) ? inext : start;
            int sj1 = csr_src[idx1];
            const float* kp1 = kv + (size_t)sj1 * KVF;
            float4 kw1 = *(const float4*)(kp1 + l8 * 4);
            float4 vw1 = *(const float4*)(kp1 + 32 + l8 * 4);

            float p = __builtin_amdgcn_fdot2(hq0, __builtin_bit_cast(h2, kw.x),
                                             0.f, false);
            p = __builtin_amdgcn_fdot2(hq1, __builtin_bit_cast(h2, kw.y), p, false);
            p = __builtin_amdgcn_fdot2(hq2, __builtin_bit_cast(h2, kw.z), p, false);
            p = __builtin_amdgcn_fdot2(hq3, __builtin_bit_cast(h2, kw.w), p, false);
            p += __shfl_xor(p, 1, 8);
            p += __shfl_xor(p, 2, 8);
            p += __shfl_xor(p, 4, 8);
            p *= 0.125f;                       // 1/sqrt(64)
            float nm = fmaxf(m, p);
            float f  = __expf(m - nm);
            float e  = __expf(p - nm);
            den = den * f + e;
            // unpack 8 bf16 v channels
            unsigned int u0 = __float_as_uint(vw.x), u1 = __float_as_uint(vw.y);
            unsigned int u2 = __float_as_uint(vw.z), u3 = __float_as_uint(vw.w);
            float v0 = __uint_as_float(u0 << 16), v1 = __uint_as_float(u0 & 0xFFFF0000u);
            float v2 = __uint_as_float(u1 << 16), v3 = __uint_as_float(u1 & 0xFFFF0000u);
            float v4 = __uint_as_float(u2 << 16), v5 = __uint_as_float(u2 & 0xFFFF0000u);
            float v6 = __uint_as_float(u3 << 16), v7 = __uint_as_float(u3 & 0xFFFF0000u);
            aa.x = aa.x * f + e * v0; aa.y = aa.y * f + e * v1;
            aa.z = aa.z * f + e * v2; aa.w = aa.w * f + e * v3;
            ab.x = ab.x * f + e * v4; ab.y = ab.y * f + e * v5;
            ab.z = ab.z * f + e * v6; ab.w = ab.w * f + e * v7;
            m = nm;
            kw = kw1; vw = vw1;
            i = inext;
        }
        // butterfly merge of the 8 groups (inactive groups: den=0, exp->0)
        float M = fmaxf(m, __shfl_xor(m, 8));
        M = fmaxf(M, __shfl_xor(M, 16));
        M = fmaxf(M, __shfl_xor(M, 32));
        float f = __expf(m - M);
        float dd = den * f;
        dd += __shfl_xor(dd, 8); dd += __shfl_xor(dd, 16); dd += __shfl_xor(dd, 32);
        aa.x *= f; aa.y *= f; aa.z *= f; aa.w *= f;
        ab.x *= f; ab.y *= f; ab.z *= f; ab.w *= f;
        aa.x += __shfl_xor(aa.x, 8); aa.x += __shfl_xor(aa.x, 16); aa.x += __shfl_xor(aa.x, 32);
        aa.y += __shfl_xor(aa.y, 8); aa.y += __shfl_xor(aa.y, 16); aa.y += __shfl_xor(aa.y, 32);
        aa.z += __shfl_xor(aa.z, 8); aa.z += __shfl_xor(aa.z, 16); aa.z += __shfl_xor(aa.z, 32);
        aa.w += __shfl_xor(aa.w, 8); aa.w += __shfl_xor(aa.w, 16); aa.w += __shfl_xor(aa.w, 32);
        ab.x += __shfl_xor(ab.x, 8); ab.x += __shfl_xor(ab.x, 16); ab.x += __shfl_xor(ab.x, 32);
        ab.y += __shfl_xor(ab.y, 8); ab.y += __shfl_xor(ab.y, 16); ab.y += __shfl_xor(ab.y, 32);
        ab.z += __shfl_xor(ab.z, 8); ab.z += __shfl_xor(ab.z, 16); ab.z += __shfl_xor(ab.z, 32);
        ab.w += __shfl_xor(ab.w, 8); ab.w += __shfl_xor(ab.w, 16); ab.w += __shfl_xor(ab.w, 32);
        float inv = 1.f / dd;
        ta.x += aa.x * inv; ta.y += aa.y * inv; ta.z += aa.z * inv; ta.w += aa.w * inv;
        tb.x += ab.x * inv; tb.y += ab.y * inv; tb.z += ab.z * inv; tb.w += ab.w * inv;
    }
    if (MODE == 1) {
        ta.x = ta.x / (1.f + __expf(-ta.x)); ta.y = ta.y / (1.f + __expf(-ta.y));
        ta.z = ta.z / (1.f + __expf(-ta.z)); ta.w = ta.w / (1.f + __expf(-ta.w));
        tb.x = tb.x / (1.f + __expf(-tb.x)); tb.y = tb.y / (1.f + __expf(-tb.y));
        tb.z = tb.z / (1.f + __expf(-tb.z)); tb.w = tb.w / (1.f + __expf(-tb.w));
    } else if (MODE == 2) {
        const float4 xa = *(const float4*)(xin + co);
        const float4 xb = *(const float4*)(xin + co + 4);
        float u;
        u = ta.x + xa.x; ta.x = u / (1.f + __expf(-u));
        u = ta.y + xa.y; ta.y = u / (1.f + __expf(-u));
        u = ta.z + xa.z; ta.z = u / (1.f + __expf(-u));
        u = ta.w + xa.w; ta.w = u / (1.f + __expf(-u));
        u = tb.x + xb.x; tb.x = u / (1.f + __expf(-u));
        u = tb.y + xb.y; tb.y = u / (1.f + __expf(-u));
        u = tb.z + xb.z; tb.z = u / (1.f + __expf(-u));
        u = tb.w + xb.w; tb.w = u / (1.f + __expf(-u));
    } else {
        const float4 za = *(const float4*)(z + co);
        const float4 zb = *(const float4*)(z + co + 4);
        ta.x += 0.1f * za.x; ta.y += 0.1f * za.y;
        ta.z += 0.1f * za.z; ta.w += 0.1f * za.w;
        tb.x += 0.1f * zb.x; tb.y += 0.1f * zb.y;
        tb.z += 0.1f * zb.z; tb.w += 0.1f * zb.w;
    }
    if (grp == 0) {
        *(float4*)(out + co) = ta;
        *(float4*)(out + co + 4) = tb;
    }
}

// ---------------------------------------------------------------------------
extern "C" void kernel_launch(void* const* d_in, const int* in_sizes, int n_in,
                              void* d_out, int out_size, void* d_ws, size_t ws_size,
                              hipStream_t stream) {
    const float* x = (const float*)d_in[0];
    const int* ei  = (const int*)d_in[1];
    const float* z = (const float*)d_in[2];
    const float* W[3][4];
    const float* B[3][4];
    for (int l = 0; l < 3; ++l)
        for (int m = 0; m < 4; ++m) {
            W[l][m] = (const float*)d_in[3 + l * 8 + m * 2];
            B[l][m] = (const float*)d_in[3 + l * 8 + m * 2 + 1];
        }
    int N = in_sizes[0] / D64;
    int E = in_sizes[1] / 2;
    size_t ND = (size_t)N * D64;

    int NB   = (N + NPB - 1) / NPB;          // buckets (391)
    int nblk = (E + CHUNK - 1) / CHUNK;      // edge chunks (196)
    int nscan = NB * nblk;                   // ~77k
    int nb2  = (nscan + 1023) / 1024;        // scan blocks (~75)

    char* p = (char*)d_ws;
    auto alloc = [&](size_t bytes) {
        char* r = p;
        p += (bytes + 255) & ~(size_t)255;
        return r;
    };
    float* q       = (float*)alloc(ND * 4);
    float* kv      = (float*)alloc((size_t)N * KVF * 4);
    float* sb      = (float*)alloc(ND * 4);
    float* hA      = (float*)alloc(ND * 4);
    int* csr_src   = (int*)alloc((size_t)E * 4);
    int2* pairs    = (int2*)alloc((size_t)E * 8);
    int* offsets   = (int*)alloc((size_t)(N + 1) * 4);
    int* bhT       = (int*)alloc((size_t)nscan * 4);
    int* partial   = (int*)alloc((size_t)nscan * 4);
    int* ebase     = (int*)alloc((size_t)nscan * 4);
    int* blockSums = (int*)alloc((size_t)nb2 * 4);
    int* flag      = (int*)alloc(4);
    float* outp    = (float*)d_out;

    hipMemsetAsync(flag, 0, 4, stream);
    int nchecks = E < 4096 ? E : 4096;
    detect_fmt<<<1, 256, 0, stream>>>(ei, nchecks, flag);
    bucket_hist<<<nblk, 256, 0, stream>>>(ei, bhT, E, nblk, NB, flag);
    scan_blocks<<<nb2, 256, 0, stream>>>(bhT, partial, blockSums, nscan);
    scan_sums<<<1, 64, 0, stream>>>(blockSums, nb2);
    make_excl<<<(nscan + 255) / 256, 256, 0, stream>>>(bhT, partial, blockSums,
                                                       ebase, nscan);
    bucket_scatter<<<nblk, 256, 0, stream>>>(ei, ebase, pairs, E, nblk, NB, flag);
    bucket_finalize<<<NB, 256, 0, stream>>>(pairs, ebase, nblk, NB,
                                            csr_src, offsets, N, E);

    int gemm_grid = (N + 63) / 64;
    int node_grid = (N + 3) / 4;

    // layer 1: x -> hA, silu
    gemm_qkvs<<<gemm_grid, 256, 0, stream>>>(x, W[0][0], B[0][0], W[0][1], B[0][1],
                                             W[0][2], B[0][2], W[0][3], B[0][3],
                                             q, kv, sb, N);
    agg_fused<1><<<node_grid, 256, 0, stream>>>(q, kv, csr_src, offsets, sb,
                                                nullptr, nullptr, hA, N);
    // layer 2: hA -> hA (residual + silu)
    gemm_qkvs<<<gemm_grid, 256, 0, stream>>>(hA, W[1][0], B[1][0], W[1][1], B[1][1],
                                             W[1][2], B[1][2], W[1][3], B[1][3],
                                             q, kv, sb, N);
    agg_fused<2><<<node_grid, 256, 0, stream>>>(q, kv, csr_src, offsets, sb,
                                                hA, nullptr, hA, N);
    // layer 3: hA -> out, + 0.1*z
    gemm_qkvs<<<gemm_grid, 256, 0, stream>>>(hA, W[2][0], B[2][0], W[2][1], B[2][1],
                                             W[2][2], B[2][2], W[2][3], B[2][3],
                                             q, kv, sb, N);
    agg_fused<3><<<node_grid, 256, 0, stream>>>(q, kv, csr_src, offsets, sb,
                                                nullptr, z, outp, N);
}

// Round 10
// 239.076 us; speedup vs baseline: 2.7798x; 1.2162x over previous
//
#include <hip/hip_runtime.h>
#include <math.h>

// ---------------------------------------------------------------------------
// PseqStepV3: 3-layer TransformerConv (heads=1), N=50000, E=800000, D=64.
//   setup: detect edge dtype; atomic-free bucketed CSR build (R8);
//          prep_w packs all 3 layers' W into bf16 hi/lo, XOR-swizzled [col][k].
//   per layer: MFMA q/kv/s GEMM (16x16x32 bf16, hi/lo split = fp32-class
//              accuracy; 96 MFMA/wave vs R9's 10.4k VALU cycles)
//              -> fused online-softmax aggregation (256B kv-row gather, fdot2)
// ---------------------------------------------------------------------------

#define D64 64
#define KVF 64       // floats per kv row: 32 words fp16 k + 32 words bf16 v
#define NPB 128      // nodes per bucket (pow2 -> bucket = dst >> 7)
#define MAXNB 512    // LDS sizing bound for bucket count (N <= 65536)
#define CHUNK 4096   // edges per block in bucket passes

typedef _Float16 h2 __attribute__((ext_vector_type(2)));
typedef __attribute__((ext_vector_type(8))) short bf16x8;
typedef __attribute__((ext_vector_type(4))) float f32x4;
typedef unsigned int uint32;

__device__ __forceinline__ unsigned short bf16_rne(float f) {
    unsigned int u = __float_as_uint(f);
    u += 0x7FFFu + ((u >> 16) & 1u);
    return (unsigned short)(u >> 16);
}

// ---- edge_index format detection: int64 rows have zero high words ----------
__global__ void detect_fmt(const int* __restrict__ ei, int nchecks, int* flag) {
    int t = blockIdx.x * blockDim.x + threadIdx.x;
    int acc = 0;
    for (int i = t; i < nchecks; i += blockDim.x * gridDim.x)
        acc |= ei[2 * i + 1];
    if (acc) atomicOr(flag, 1);   // nonzero => plain int32 layout
}

__device__ __forceinline__ int load_src(const int* ei, int e, int E, int is64) {
    return is64 ? ei[2 * e] : ei[e];
}
__device__ __forceinline__ int load_dst(const int* ei, int e, int E, int is64) {
    return is64 ? ei[2 * E + 2 * e] : ei[E + e];
}

// ---- CSR build: bucketed, atomic-free (LDS atomics only) -------------------
__global__ void bucket_hist(const int* __restrict__ ei, int* __restrict__ bhT,
                            int E, int nblk, int NB, const int* __restrict__ flag) {
    __shared__ int h[MAXNB];
    int blk = blockIdx.x, tid = threadIdx.x;
    for (int i = tid; i < NB; i += 256) h[i] = 0;
    __syncthreads();
    int is64 = (*flag == 0);
    int e1 = blk * CHUNK + CHUNK; if (e1 > E) e1 = E;
    for (int e = blk * CHUNK + tid; e < e1; e += 256)
        atomicAdd(&h[load_dst(ei, e, E, is64) >> 7], 1);
    __syncthreads();
    for (int i = tid; i < NB; i += 256) bhT[i * nblk + blk] = h[i];
}

__global__ void scan_blocks(const int* __restrict__ counts, int* __restrict__ partial,
                            int* __restrict__ blockSums, int n) {
    int tid = threadIdx.x;                 // 256
    int base = blockIdx.x * 1024 + tid * 4;
    int4 c = make_int4(0, 0, 0, 0);
    if (base + 3 < n) c = *(const int4*)&counts[base];
    else {
        if (base + 0 < n) c.x = counts[base + 0];
        if (base + 1 < n) c.y = counts[base + 1];
        if (base + 2 < n) c.z = counts[base + 2];
        if (base + 3 < n) c.w = counts[base + 3];
    }
    int s1 = c.x, s2 = s1 + c.y, s3 = s2 + c.z, s4 = s3 + c.w;
    int lane = tid & 63, wave = tid >> 6;
    int v = s4;
#pragma unroll
    for (int off = 1; off < 64; off <<= 1) {
        int t = __shfl_up(v, off);
        if (lane >= off) v += t;
    }
    __shared__ int wsum[4];
    if (lane == 63) wsum[wave] = v;
    __syncthreads();
    int wpre = 0;
    for (int w = 0; w < wave; ++w) wpre += wsum[w];
    int pre = wpre + v - s4;
    if (base + 0 < n) partial[base + 0] = pre + s1;
    if (base + 1 < n) partial[base + 1] = pre + s2;
    if (base + 2 < n) partial[base + 2] = pre + s3;
    if (base + 3 < n) partial[base + 3] = pre + s4;
    if (tid == 255) blockSums[blockIdx.x] = wsum[0] + wsum[1] + wsum[2] + wsum[3];
}

__global__ void scan_sums(int* __restrict__ bs, int nb) {
    int lane = threadIdx.x;                // 64
    int carry = 0;
    for (int b0 = 0; b0 < nb; b0 += 64) {
        int i = b0 + lane;
        int val = (i < nb) ? bs[i] : 0;
        int v = val;
#pragma unroll
        for (int off = 1; off < 64; off <<= 1) {
            int t = __shfl_up(v, off);
            if (lane >= off) v += t;
        }
        if (i < nb) bs[i] = carry + v - val;   // exclusive
        carry += __shfl(v, 63);
    }
}

__global__ void make_excl(const int* __restrict__ bh, const int* __restrict__ partial,
                          const int* __restrict__ bs, int* __restrict__ ebase, int n) {
    int i = blockIdx.x * 256 + threadIdx.x;
    if (i >= n) return;
    ebase[i] = partial[i] + bs[i >> 10] - bh[i];   // exclusive global scan
}

__global__ void bucket_scatter(const int* __restrict__ ei, const int* __restrict__ ebase,
                               int2* __restrict__ pairs, int E, int nblk, int NB,
                               const int* __restrict__ flag) {
    __shared__ int cur[MAXNB];
    int blk = blockIdx.x, tid = threadIdx.x;
    for (int i = tid; i < NB; i += 256) cur[i] = ebase[i * nblk + blk];
    __syncthreads();
    int is64 = (*flag == 0);
    int e1 = blk * CHUNK + CHUNK; if (e1 > E) e1 = E;
    for (int e = blk * CHUNK + tid; e < e1; e += 256) {
        int s = load_src(ei, e, E, is64);
        int d = load_dst(ei, e, E, is64);
        int pos = atomicAdd(&cur[d >> 7], 1);
        pairs[pos] = make_int2(s, d);
    }
}

__global__ void bucket_finalize(const int2* __restrict__ pairs,
                                const int* __restrict__ ebase, int nblk, int NB,
                                int* __restrict__ csr_src, int* __restrict__ offsets,
                                int N, int E) {
    __shared__ int hist[NPB];
    __shared__ int cur[NPB];
    int b = blockIdx.x, tid = threadIdx.x;
    int n0 = b * NPB;
    int cnt = N - n0; if (cnt > NPB) cnt = NPB;
    if (cnt <= 0) return;
    int estart = ebase[b * nblk];
    int eend = (b + 1 < NB) ? ebase[(b + 1) * nblk] : E;
    for (int i = tid; i < cnt; i += 256) hist[i] = 0;
    __syncthreads();
    for (int e = estart + tid; e < eend; e += 256)
        atomicAdd(&hist[pairs[e].y - n0], 1);
    __syncthreads();
    if (tid == 0) {
        int run = estart;
        for (int i = 0; i < cnt; ++i) {
            cur[i] = run;
            offsets[n0 + i] = run;
            run += hist[i];
        }
    }
    if (b == 0 && tid == 1) offsets[N] = E;
    __syncthreads();
    for (int e = estart + tid; e < eend; e += 256) {
        int2 pr = pairs[e];
        int pos = atomicAdd(&cur[pr.y - n0], 1);
        csr_src[pos] = pr.x;
    }
}

// ---- W prep: bf16 hi/lo split, [col][k] layout, XOR-swizzled ---------------
// Per (layer, mat) block: cols mat*64..+63 of the layer's 256-wide W block.
// Word kw of col holds k=2kw,2kw+1; byte addr within col row = (kw*4) ^
// ((col&7)<<4)  -> ds_read_b128 of 8 k-consecutive bf16 is 2-way-conflict-free.
__global__ void prep_w(const float* W0, const float* W1, const float* W2,
                       const float* W3, const float* W4, const float* W5,
                       const float* W6, const float* W7, const float* W8,
                       const float* W9, const float* W10, const float* W11,
                       uint32* __restrict__ wpack) {
    const float* Wm;
    switch (blockIdx.x) {
        case 0: Wm = W0; break;  case 1: Wm = W1; break;
        case 2: Wm = W2; break;  case 3: Wm = W3; break;
        case 4: Wm = W4; break;  case 5: Wm = W5; break;
        case 6: Wm = W6; break;  case 7: Wm = W7; break;
        case 8: Wm = W8; break;  case 9: Wm = W9; break;
        case 10: Wm = W10; break; default: Wm = W11; break;
    }
    int layer = blockIdx.x >> 2, mat = blockIdx.x & 3;
    uint32* hiB = wpack + layer * 16384;
    uint32* loB = hiB + 8192;
    int d = threadIdx.x & 63;
    int cg = threadIdx.x >> 6;
    int col = mat * 64 + d;
    for (int kw = cg; kw < 32; kw += 4) {
        float w0 = Wm[(2 * kw) * 64 + d];
        float w1 = Wm[(2 * kw + 1) * 64 + d];
        unsigned short h0 = bf16_rne(w0);
        unsigned short h1 = bf16_rne(w1);
        float r0 = w0 - __uint_as_float(((uint32)h0) << 16);
        float r1 = w1 - __uint_as_float(((uint32)h1) << 16);
        unsigned short l0 = bf16_rne(r0);
        unsigned short l1 = bf16_rne(r1);
        int sw = ((kw * 4) ^ ((col & 7) << 4)) >> 2;
        hiB[col * 32 + sw] = (uint32)h0 | ((uint32)h1 << 16);
        loB[col * 32 + sw] = (uint32)l0 | ((uint32)l1 << 16);
    }
}

// ---- MFMA q/kv/s GEMM ------------------------------------------------------
// Block: 4 waves x 16 rows = 64 rows; wave computes its 16 rows x all 256 cols
// (cols 0-63 q | 64-127 k | 128-191 v | 192-255 s) via 16 col-tiles of
// 16x16x32 bf16 MFMA, 2 K-steps, 3 hi/lo passes (hi*hi + hi*lo + lo*hi).
// Fragments (guide-verified): A/B idx = lane&15, k = (lane>>4)*8+j;
// D: col = lane&15, row = (lane>>4)*4+reg.
__launch_bounds__(256)
__global__ void gemm_mfma(const float* __restrict__ x, const uint32* __restrict__ wpackL,
                          const float* __restrict__ bq, const float* __restrict__ bk,
                          const float* __restrict__ bv, const float* __restrict__ bs,
                          float* __restrict__ q, float* __restrict__ kv,
                          float* __restrict__ s, int n) {
    __shared__ uint32 wlds[16384];   // 64 KiB: hi [0,32KB), lo [32KB,64KB)
    int tid = threadIdx.x;
#pragma unroll
    for (int r = 0; r < 16; ++r) {
        int w4 = r * 1024 + tid * 4;
        *(uint4*)&wlds[w4] = *(const uint4*)&wpackL[w4];
    }
    __syncthreads();

    int lane = tid & 63, wave = tid >> 6;
    int row0 = blockIdx.x * 64 + wave * 16;
    int arow = row0 + (lane & 15);
    int kgrp = (lane >> 4) * 8;
    bool rowok = arow < n;
    const float* xr = x + (size_t)(rowok ? arow : 0) * D64;

    bf16x8 ahi[2], alo[2];
#pragma unroll
    for (int st = 0; st < 2; ++st) {
        float4 xa = rowok ? *(const float4*)(xr + st * 32 + kgrp)
                          : make_float4(0.f, 0.f, 0.f, 0.f);
        float4 xb = rowok ? *(const float4*)(xr + st * 32 + kgrp + 4)
                          : make_float4(0.f, 0.f, 0.f, 0.f);
        float xs[8] = {xa.x, xa.y, xa.z, xa.w, xb.x, xb.y, xb.z, xb.w};
#pragma unroll
        for (int j = 0; j < 8; ++j) {
            unsigned short h = bf16_rne(xs[j]);
            float rem = xs[j] - __uint_as_float(((uint32)h) << 16);
            ahi[st][j] = (short)h;
            alo[st][j] = (short)bf16_rne(rem);
        }
    }

    f32x4 acc[16];
#pragma unroll
    for (int t = 0; t < 16; ++t) acc[t] = f32x4{0.f, 0.f, 0.f, 0.f};

#pragma unroll
    for (int t = 0; t < 16; ++t) {
        int col = t * 16 + (lane & 15);
#pragma unroll
        for (int st = 0; st < 2; ++st) {
            int kidx = st * 32 + kgrp;
            int boff = col * 128 + ((kidx * 2) ^ ((col & 7) << 4));
            bf16x8 bhi = *(const bf16x8*)((const char*)wlds + boff);
            bf16x8 blo = *(const bf16x8*)((const char*)wlds + boff + 32768);
            acc[t] = __builtin_amdgcn_mfma_f32_16x16x32_bf16(alo[st], bhi, acc[t], 0, 0, 0);
            acc[t] = __builtin_amdgcn_mfma_f32_16x16x32_bf16(ahi[st], blo, acc[t], 0, 0, 0);
            acc[t] = __builtin_amdgcn_mfma_f32_16x16x32_bf16(ahi[st], bhi, acc[t], 0, 0, 0);
        }
    }

    int drow0 = row0 + (lane >> 4) * 4;
    int c16 = lane & 15;
    // q tiles 0-3
#pragma unroll
    for (int t = 0; t < 4; ++t) {
        float bb = bq[t * 16 + c16];
#pragma unroll
        for (int r = 0; r < 4; ++r) {
            int row = drow0 + r;
            if (row < n) q[(size_t)row * D64 + t * 16 + c16] = acc[t][r] + bb;
        }
    }
    // s tiles 12-15
#pragma unroll
    for (int t = 0; t < 4; ++t) {
        float bb = bs[t * 16 + c16];
#pragma unroll
        for (int r = 0; r < 4; ++r) {
            int row = drow0 + r;
            if (row < n) s[(size_t)row * D64 + t * 16 + c16] = acc[12 + t][r] + bb;
        }
    }
    // k tiles 4-7 (fp16, kv words 0-31) + v tiles 8-11 (bf16, kv words 32-63)
#pragma unroll
    for (int t = 0; t < 4; ++t) {
        float bkk = bk[t * 16 + c16];
        float bvv = bv[t * 16 + c16];
        int c = t * 16 + c16;
#pragma unroll
        for (int r = 0; r < 4; ++r) {
            int row = drow0 + r;
            float kval = acc[4 + t][r] + bkk;
            float vval = acc[8 + t][r] + bvv;
            uint32 kh = (uint32)__builtin_bit_cast(unsigned short, (_Float16)kval);
            uint32 kp = (uint32)__shfl_xor((int)kh, 1);
            uint32 kword = (lane & 1) ? (kp | (kh << 16)) : (kh | (kp << 16));
            uint32 vh = (uint32)bf16_rne(vval);
            uint32 vp = (uint32)__shfl_xor((int)vh, 1);
            uint32 vword = (lane & 1) ? (vp | (vh << 16)) : (vh | (vp << 16));
            if (row < n && !(lane & 1)) {
                uint32* rowp = (uint32*)(kv + (size_t)row * KVF);
                rowp[c >> 1] = kword;
                rowp[32 + (c >> 1)] = vword;
            }
        }
    }
}

// ---- fused edge-score + online-softmax aggregation + epilogue --------------
// (unchanged from R9) Wave = 1 node; 8 groups x 8 lanes; 256B kv-row gather;
// fdot2 fp16 scores; online softmax; butterfly merge.
template <int MODE>
__launch_bounds__(256)
__global__ void agg_fused(const float* __restrict__ q, const float* __restrict__ kv,
                          const int* __restrict__ csr_src,
                          const int* __restrict__ offsets,
                          const float* __restrict__ sbuf, const float* __restrict__ xin,
                          const float* __restrict__ z, float* __restrict__ out, int n) {
    int node = blockIdx.x * 4 + (threadIdx.x >> 6);
    if (node >= n) return;
    int lane = threadIdx.x & 63;
    int grp = lane >> 3, l8 = lane & 7;
    int start = offsets[node], end = offsets[node + 1];
    size_t co = (size_t)node * D64 + l8 * 8;
    float4 ta = *(const float4*)(sbuf + co);
    float4 tb = *(const float4*)(sbuf + co + 4);

    if (end > start) {
        const float4 qa = *(const float4*)(q + co);
        const float4 qb = *(const float4*)(q + co + 4);
        h2 hq0, hq1, hq2, hq3;
        hq0[0] = (_Float16)qa.x; hq0[1] = (_Float16)qa.y;
        hq1[0] = (_Float16)qa.z; hq1[1] = (_Float16)qa.w;
        hq2[0] = (_Float16)qb.x; hq2[1] = (_Float16)qb.y;
        hq3[0] = (_Float16)qb.z; hq3[1] = (_Float16)qb.w;
        float m = -3.0e38f, den = 0.f;
        float4 aa = make_float4(0.f, 0.f, 0.f, 0.f);
        float4 ab = make_float4(0.f, 0.f, 0.f, 0.f);

        int i = start + grp;
        int idx0 = (i < end) ? i : start;
        int sj0 = csr_src[idx0];
        const float* kp0 = kv + (size_t)sj0 * KVF;
        float4 kw = *(const float4*)(kp0 + l8 * 4);
        float4 vw = *(const float4*)(kp0 + 32 + l8 * 4);

        while (i < end) {
            int inext = i + 8;
            int idx1 = (inext < end) ? inext : start;
            int sj1 = csr_src[idx1];
            const float* kp1 = kv + (size_t)sj1 * KVF;
            float4 kw1 = *(const float4*)(kp1 + l8 * 4);
            float4 vw1 = *(const float4*)(kp1 + 32 + l8 * 4);

            float p = __builtin_amdgcn_fdot2(hq0, __builtin_bit_cast(h2, kw.x),
                                             0.f, false);
            p = __builtin_amdgcn_fdot2(hq1, __builtin_bit_cast(h2, kw.y), p, false);
            p = __builtin_amdgcn_fdot2(hq2, __builtin_bit_cast(h2, kw.z), p, false);
            p = __builtin_amdgcn_fdot2(hq3, __builtin_bit_cast(h2, kw.w), p, false);
            p += __shfl_xor(p, 1, 8);
            p += __shfl_xor(p, 2, 8);
            p += __shfl_xor(p, 4, 8);
            p *= 0.125f;                       // 1/sqrt(64)
            float nm = fmaxf(m, p);
            float f  = __expf(m - nm);
            float e  = __expf(p - nm);
            den = den * f + e;
            unsigned int u0 = __float_as_uint(vw.x), u1 = __float_as_uint(vw.y);
            unsigned int u2 = __float_as_uint(vw.z), u3 = __float_as_uint(vw.w);
            float v0 = __uint_as_float(u0 << 16), v1 = __uint_as_float(u0 & 0xFFFF0000u);
            float v2 = __uint_as_float(u1 << 16), v3 = __uint_as_float(u1 & 0xFFFF0000u);
            float v4 = __uint_as_float(u2 << 16), v5 = __uint_as_float(u2 & 0xFFFF0000u);
            float v6 = __uint_as_float(u3 << 16), v7 = __uint_as_float(u3 & 0xFFFF0000u);
            aa.x = aa.x * f + e * v0; aa.y = aa.y * f + e * v1;
            aa.z = aa.z * f + e * v2; aa.w = aa.w * f + e * v3;
            ab.x = ab.x * f + e * v4; ab.y = ab.y * f + e * v5;
            ab.z = ab.z * f + e * v6; ab.w = ab.w * f + e * v7;
            m = nm;
            kw = kw1; vw = vw1;
            i = inext;
        }
        float M = fmaxf(m, __shfl_xor(m, 8));
        M = fmaxf(M, __shfl_xor(M, 16));
        M = fmaxf(M, __shfl_xor(M, 32));
        float f = __expf(m - M);
        float dd = den * f;
        dd += __shfl_xor(dd, 8); dd += __shfl_xor(dd, 16); dd += __shfl_xor(dd, 32);
        aa.x *= f; aa.y *= f; aa.z *= f; aa.w *= f;
        ab.x *= f; ab.y *= f; ab.z *= f; ab.w *= f;
        aa.x += __shfl_xor(aa.x, 8); aa.x += __shfl_xor(aa.x, 16); aa.x += __shfl_xor(aa.x, 32);
        aa.y += __shfl_xor(aa.y, 8); aa.y += __shfl_xor(aa.y, 16); aa.y += __shfl_xor(aa.y, 32);
        aa.z += __shfl_xor(aa.z, 8); aa.z += __shfl_xor(aa.z, 16); aa.z += __shfl_xor(aa.z, 32);
        aa.w += __shfl_xor(aa.w, 8); aa.w += __shfl_xor(aa.w, 16); aa.w += __shfl_xor(aa.w, 32);
        ab.x += __shfl_xor(ab.x, 8); ab.x += __shfl_xor(ab.x, 16); ab.x += __shfl_xor(ab.x, 32);
        ab.y += __shfl_xor(ab.y, 8); ab.y += __shfl_xor(ab.y, 16); ab.y += __shfl_xor(ab.y, 32);
        ab.z += __shfl_xor(ab.z, 8); ab.z += __shfl_xor(ab.z, 16); ab.z += __shfl_xor(ab.z, 32);
        ab.w += __shfl_xor(ab.w, 8); ab.w += __shfl_xor(ab.w, 16); ab.w += __shfl_xor(ab.w, 32);
        float inv = 1.f / dd;
        ta.x += aa.x * inv; ta.y += aa.y * inv; ta.z += aa.z * inv; ta.w += aa.w * inv;
        tb.x += ab.x * inv; tb.y += ab.y * inv; tb.z += ab.z * inv; tb.w += ab.w * inv;
    }
    if (MODE == 1) {
        ta.x = ta.x / (1.f + __expf(-ta.x)); ta.y = ta.y / (1.f + __expf(-ta.y));
        ta.z = ta.z / (1.f + __expf(-ta.z)); ta.w = ta.w / (1.f + __expf(-ta.w));
        tb.x = tb.x / (1.f + __expf(-tb.x)); tb.y = tb.y / (1.f + __expf(-tb.y));
        tb.z = tb.z / (1.f + __expf(-tb.z)); tb.w = tb.w / (1.f + __expf(-tb.w));
    } else if (MODE == 2) {
        const float4 xa = *(const float4*)(xin + co);
        const float4 xb = *(const float4*)(xin + co + 4);
        float u;
        u = ta.x + xa.x; ta.x = u / (1.f + __expf(-u));
        u = ta.y + xa.y; ta.y = u / (1.f + __expf(-u));
        u = ta.z + xa.z; ta.z = u / (1.f + __expf(-u));
        u = ta.w + xa.w; ta.w = u / (1.f + __expf(-u));
        u = tb.x + xb.x; tb.x = u / (1.f + __expf(-u));
        u = tb.y + xb.y; tb.y = u / (1.f + __expf(-u));
        u = tb.z + xb.z; tb.z = u / (1.f + __expf(-u));
        u = tb.w + xb.w; tb.w = u / (1.f + __expf(-u));
    } else {
        const float4 za = *(const float4*)(z + co);
        const float4 zb = *(const float4*)(z + co + 4);
        ta.x += 0.1f * za.x; ta.y += 0.1f * za.y;
        ta.z += 0.1f * za.z; ta.w += 0.1f * za.w;
        tb.x += 0.1f * zb.x; tb.y += 0.1f * zb.y;
        tb.z += 0.1f * zb.z; tb.w += 0.1f * zb.w;
    }
    if (grp == 0) {
        *(float4*)(out + co) = ta;
        *(float4*)(out + co + 4) = tb;
    }
}

// ---------------------------------------------------------------------------
extern "C" void kernel_launch(void* const* d_in, const int* in_sizes, int n_in,
                              void* d_out, int out_size, void* d_ws, size_t ws_size,
                              hipStream_t stream) {
    const float* x = (const float*)d_in[0];
    const int* ei  = (const int*)d_in[1];
    const float* z = (const float*)d_in[2];
    const float* W[3][4];
    const float* B[3][4];
    for (int l = 0; l < 3; ++l)
        for (int m = 0; m < 4; ++m) {
            W[l][m] = (const float*)d_in[3 + l * 8 + m * 2];
            B[l][m] = (const float*)d_in[3 + l * 8 + m * 2 + 1];
        }
    int N = in_sizes[0] / D64;
    int E = in_sizes[1] / 2;
    size_t ND = (size_t)N * D64;

    int NB   = (N + NPB - 1) / NPB;          // buckets (391)
    int nblk = (E + CHUNK - 1) / CHUNK;      // edge chunks (196)
    int nscan = NB * nblk;                   // ~77k
    int nb2  = (nscan + 1023) / 1024;        // scan blocks (~75)

    char* p = (char*)d_ws;
    auto alloc = [&](size_t bytes) {
        char* r = p;
        p += (bytes + 255) & ~(size_t)255;
        return r;
    };
    float* q       = (float*)alloc(ND * 4);
    float* kv      = (float*)alloc((size_t)N * KVF * 4);
    float* sb      = (float*)alloc(ND * 4);
    float* hA      = (float*)alloc(ND * 4);
    int* csr_src   = (int*)alloc((size_t)E * 4);
    int2* pairs    = (int2*)alloc((size_t)E * 8);
    int* offsets   = (int*)alloc((size_t)(N + 1) * 4);
    int* bhT       = (int*)alloc((size_t)nscan * 4);
    int* partial   = (int*)alloc((size_t)nscan * 4);
    int* ebase     = (int*)alloc((size_t)nscan * 4);
    int* blockSums = (int*)alloc((size_t)nb2 * 4);
    uint32* wpack  = (uint32*)alloc(3 * 16384 * 4);
    int* flag      = (int*)alloc(4);
    float* outp    = (float*)d_out;

    hipMemsetAsync(flag, 0, 4, stream);
    int nchecks = E < 4096 ? E : 4096;
    detect_fmt<<<1, 256, 0, stream>>>(ei, nchecks, flag);
    prep_w<<<12, 256, 0, stream>>>(W[0][0], W[0][1], W[0][2], W[0][3],
                                   W[1][0], W[1][1], W[1][2], W[1][3],
                                   W[2][0], W[2][1], W[2][2], W[2][3], wpack);
    bucket_hist<<<nblk, 256, 0, stream>>>(ei, bhT, E, nblk, NB, flag);
    scan_blocks<<<nb2, 256, 0, stream>>>(bhT, partial, blockSums, nscan);
    scan_sums<<<1, 64, 0, stream>>>(blockSums, nb2);
    make_excl<<<(nscan + 255) / 256, 256, 0, stream>>>(bhT, partial, blockSums,
                                                       ebase, nscan);
    bucket_scatter<<<nblk, 256, 0, stream>>>(ei, ebase, pairs, E, nblk, NB, flag);
    bucket_finalize<<<NB, 256, 0, stream>>>(pairs, ebase, nblk, NB,
                                            csr_src, offsets, N, E);

    int gemm_grid = (N + 63) / 64;
    int node_grid = (N + 3) / 4;

    // layer 1: x -> hA, silu
    gemm_mfma<<<gemm_grid, 256, 0, stream>>>(x, wpack, B[0][0], B[0][1],
                                             B[0][2], B[0][3], q, kv, sb, N);
    agg_fused<1><<<node_grid, 256, 0, stream>>>(q, kv, csr_src, offsets, sb,
                                                nullptr, nullptr, hA, N);
    // layer 2: hA -> hA (residual + silu)
    gemm_mfma<<<gemm_grid, 256, 0, stream>>>(hA, wpack + 16384, B[1][0], B[1][1],
                                             B[1][2], B[1][3], q, kv, sb, N);
    agg_fused<2><<<node_grid, 256, 0, stream>>>(q, kv, csr_src, offsets, sb,
                                                hA, nullptr, hA, N);
    // layer 3: hA -> out, + 0.1*z
    gemm_mfma<<<gemm_grid, 256, 0, stream>>>(hA, wpack + 32768, B[2][0], B[2][1],
                                             B[2][2], B[2][3], q, kv, sb, N);
    agg_fused<3><<<node_grid, 256, 0, stream>>>(q, kv, csr_src, offsets, sb,
                                                nullptr, z, outp, N);
}

// Round 11
// 235.248 us; speedup vs baseline: 2.8251x; 1.0163x over previous
//
#include <hip/hip_runtime.h>
#include <math.h>

// ---------------------------------------------------------------------------
// PseqStepV3: 3-layer TransformerConv (heads=1), N=50000, E=800000, D=64.
//   setup: detect edge dtype; atomic-free bucketed CSR build (packed 32-bit
//          src|dst words, R11); prep_w packs W into bf16 hi/lo, swizzled.
//   per layer: MFMA q/kv/s GEMM (16x16x32 bf16 hi/lo split)
//              -> fused online-softmax aggregation (256B kv-row gather,
//                 fdot2 fp16 scores, raw v_exp/v_rcp transcendentals)
// ---------------------------------------------------------------------------

#define D64 64
#define KVF 64       // floats per kv row: 32 words fp16 k + 32 words bf16 v
#define NPB 128      // nodes per bucket (pow2 -> bucket = dst >> 7)
#define MAXNB 512    // LDS sizing bound for bucket count (N <= 65536)
#define CHUNK 4096   // edges per block in bucket passes

typedef _Float16 h2 __attribute__((ext_vector_type(2)));
typedef __attribute__((ext_vector_type(8))) short bf16x8;
typedef __attribute__((ext_vector_type(4))) float f32x4;
typedef unsigned int uint32;

__device__ __forceinline__ unsigned short bf16_rne(float f) {
    unsigned int u = __float_as_uint(f);
    u += 0x7FFFu + ((u >> 16) & 1u);
    return (unsigned short)(u >> 16);
}
// raw-HW transcendentals: v_exp_f32 (2 instr) / v_rcp_f32 (1 instr); ~1-2 ulp
__device__ __forceinline__ float fexp(float x) {
    return __builtin_amdgcn_exp2f(x * 1.44269504089f);
}
__device__ __forceinline__ float frcp(float x) {
    return __builtin_amdgcn_rcpf(x);
}

// ---- edge_index format detection: int64 rows have zero high words ----------
__global__ void detect_fmt(const int* __restrict__ ei, int nchecks, int* flag) {
    int t = blockIdx.x * blockDim.x + threadIdx.x;
    int acc = 0;
    for (int i = t; i < nchecks; i += blockDim.x * gridDim.x)
        acc |= ei[2 * i + 1];
    if (acc) atomicOr(flag, 1);   // nonzero => plain int32 layout
}

__device__ __forceinline__ int load_src(const int* ei, int e, int E, int is64) {
    return is64 ? ei[2 * e] : ei[e];
}
__device__ __forceinline__ int load_dst(const int* ei, int e, int E, int is64) {
    return is64 ? ei[2 * E + 2 * e] : ei[E + e];
}

// ---- CSR build: bucketed, atomic-free (LDS atomics only) -------------------
// P1: LDS bucket histogram + emit packed word src | dst<<16 (both < 2^16)
__global__ void hist_pack(const int* __restrict__ ei, int* __restrict__ bhT,
                          uint32* __restrict__ pc, int E, int nblk, int NB,
                          const int* __restrict__ flag) {
    __shared__ int h[MAXNB];
    int blk = blockIdx.x, tid = threadIdx.x;
    for (int i = tid; i < NB; i += 256) h[i] = 0;
    __syncthreads();
    int is64 = (*flag == 0);
    int e1 = blk * CHUNK + CHUNK; if (e1 > E) e1 = E;
    for (int e = blk * CHUNK + tid; e < e1; e += 256) {
        int s = load_src(ei, e, E, is64);
        int d = load_dst(ei, e, E, is64);
        pc[e] = (uint32)s | ((uint32)d << 16);
        atomicAdd(&h[d >> 7], 1);
    }
    __syncthreads();
    for (int i = tid; i < NB; i += 256) bhT[i * nblk + blk] = h[i];
}

__global__ void scan_blocks(const int* __restrict__ counts, int* __restrict__ partial,
                            int* __restrict__ blockSums, int n) {
    int tid = threadIdx.x;                 // 256
    int base = blockIdx.x * 1024 + tid * 4;
    int4 c = make_int4(0, 0, 0, 0);
    if (base + 3 < n) c = *(const int4*)&counts[base];
    else {
        if (base + 0 < n) c.x = counts[base + 0];
        if (base + 1 < n) c.y = counts[base + 1];
        if (base + 2 < n) c.z = counts[base + 2];
        if (base + 3 < n) c.w = counts[base + 3];
    }
    int s1 = c.x, s2 = s1 + c.y, s3 = s2 + c.z, s4 = s3 + c.w;
    int lane = tid & 63, wave = tid >> 6;
    int v = s4;
#pragma unroll
    for (int off = 1; off < 64; off <<= 1) {
        int t = __shfl_up(v, off);
        if (lane >= off) v += t;
    }
    __shared__ int wsum[4];
    if (lane == 63) wsum[wave] = v;
    __syncthreads();
    int wpre = 0;
    for (int w = 0; w < wave; ++w) wpre += wsum[w];
    int pre = wpre + v - s4;
    if (base + 0 < n) partial[base + 0] = pre + s1;
    if (base + 1 < n) partial[base + 1] = pre + s2;
    if (base + 2 < n) partial[base + 2] = pre + s3;
    if (base + 3 < n) partial[base + 3] = pre + s4;
    if (tid == 255) blockSums[blockIdx.x] = wsum[0] + wsum[1] + wsum[2] + wsum[3];
}

__global__ void scan_sums(int* __restrict__ bs, int nb) {
    int lane = threadIdx.x;                // 64
    int carry = 0;
    for (int b0 = 0; b0 < nb; b0 += 64) {
        int i = b0 + lane;
        int val = (i < nb) ? bs[i] : 0;
        int v = val;
#pragma unroll
        for (int off = 1; off < 64; off <<= 1) {
            int t = __shfl_up(v, off);
            if (lane >= off) v += t;
        }
        if (i < nb) bs[i] = carry + v - val;   // exclusive
        carry += __shfl(v, 63);
    }
}

__global__ void make_excl(const int* __restrict__ bh, const int* __restrict__ partial,
                          const int* __restrict__ bs, int* __restrict__ ebase, int n) {
    int i = blockIdx.x * 256 + threadIdx.x;
    if (i >= n) return;
    ebase[i] = partial[i] + bs[i >> 10] - bh[i];   // exclusive global scan
}

// P3: replay packed words; LDS cursors -> bucket-sorted pairs32
__global__ void bucket_scatter(const uint32* __restrict__ pc, const int* __restrict__ ebase,
                               uint32* __restrict__ pairs, int E, int nblk, int NB) {
    __shared__ int cur[MAXNB];
    int blk = blockIdx.x, tid = threadIdx.x;
    for (int i = tid; i < NB; i += 256) cur[i] = ebase[i * nblk + blk];
    __syncthreads();
    int e1 = blk * CHUNK + CHUNK; if (e1 > E) e1 = E;
    for (int e = blk * CHUNK + tid; e < e1; e += 256) {
        uint32 w = pc[e];
        int pos = atomicAdd(&cur[w >> 23], 1);   // bucket = dst >> 7
        pairs[pos] = w;
    }
}

// P4: one WG per bucket: local node hist -> local scan -> offsets + csr_src
__global__ void bucket_finalize(const uint32* __restrict__ pairs,
                                const int* __restrict__ ebase, int nblk, int NB,
                                int* __restrict__ csr_src, int* __restrict__ offsets,
                                int N, int E) {
    __shared__ int hist[NPB];
    __shared__ int cur[NPB];
    int b = blockIdx.x, tid = threadIdx.x;
    int n0 = b * NPB;
    int cnt = N - n0; if (cnt > NPB) cnt = NPB;
    if (cnt <= 0) return;
    int estart = ebase[b * nblk];
    int eend = (b + 1 < NB) ? ebase[(b + 1) * nblk] : E;
    for (int i = tid; i < cnt; i += 256) hist[i] = 0;
    __syncthreads();
    for (int e = estart + tid; e < eend; e += 256)
        atomicAdd(&hist[(int)(pairs[e] >> 16) - n0], 1);
    __syncthreads();
    if (tid == 0) {
        int run = estart;
        for (int i = 0; i < cnt; ++i) {
            cur[i] = run;
            offsets[n0 + i] = run;
            run += hist[i];
        }
    }
    if (b == 0 && tid == 1) offsets[N] = E;
    __syncthreads();
    for (int e = estart + tid; e < eend; e += 256) {
        uint32 w = pairs[e];
        int pos = atomicAdd(&cur[(int)(w >> 16) - n0], 1);
        csr_src[pos] = (int)(w & 0xFFFFu);
    }
}

// ---- W prep: bf16 hi/lo split, [col][k] layout, XOR-swizzled ---------------
__global__ void prep_w(const float* W0, const float* W1, const float* W2,
                       const float* W3, const float* W4, const float* W5,
                       const float* W6, const float* W7, const float* W8,
                       const float* W9, const float* W10, const float* W11,
                       uint32* __restrict__ wpack) {
    const float* Wm;
    switch (blockIdx.x) {
        case 0: Wm = W0; break;  case 1: Wm = W1; break;
        case 2: Wm = W2; break;  case 3: Wm = W3; break;
        case 4: Wm = W4; break;  case 5: Wm = W5; break;
        case 6: Wm = W6; break;  case 7: Wm = W7; break;
        case 8: Wm = W8; break;  case 9: Wm = W9; break;
        case 10: Wm = W10; break; default: Wm = W11; break;
    }
    int layer = blockIdx.x >> 2, mat = blockIdx.x & 3;
    uint32* hiB = wpack + layer * 16384;
    uint32* loB = hiB + 8192;
    int d = threadIdx.x & 63;
    int cg = threadIdx.x >> 6;
    int col = mat * 64 + d;
    for (int kw = cg; kw < 32; kw += 4) {
        float w0 = Wm[(2 * kw) * 64 + d];
        float w1 = Wm[(2 * kw + 1) * 64 + d];
        unsigned short h0 = bf16_rne(w0);
        unsigned short h1 = bf16_rne(w1);
        float r0 = w0 - __uint_as_float(((uint32)h0) << 16);
        float r1 = w1 - __uint_as_float(((uint32)h1) << 16);
        unsigned short l0 = bf16_rne(r0);
        unsigned short l1 = bf16_rne(r1);
        int sw = ((kw * 4) ^ ((col & 7) << 4)) >> 2;
        hiB[col * 32 + sw] = (uint32)h0 | ((uint32)h1 << 16);
        loB[col * 32 + sw] = (uint32)l0 | ((uint32)l1 << 16);
    }
}

// ---- MFMA q/kv/s GEMM (unchanged from R10) ---------------------------------
__launch_bounds__(256)
__global__ void gemm_mfma(const float* __restrict__ x, const uint32* __restrict__ wpackL,
                          const float* __restrict__ bq, const float* __restrict__ bk,
                          const float* __restrict__ bv, const float* __restrict__ bs,
                          float* __restrict__ q, float* __restrict__ kv,
                          float* __restrict__ s, int n) {
    __shared__ uint32 wlds[16384];   // 64 KiB: hi [0,32KB), lo [32KB,64KB)
    int tid = threadIdx.x;
#pragma unroll
    for (int r = 0; r < 16; ++r) {
        int w4 = r * 1024 + tid * 4;
        *(uint4*)&wlds[w4] = *(const uint4*)&wpackL[w4];
    }
    __syncthreads();

    int lane = tid & 63, wave = tid >> 6;
    int row0 = blockIdx.x * 64 + wave * 16;
    int arow = row0 + (lane & 15);
    int kgrp = (lane >> 4) * 8;
    bool rowok = arow < n;
    const float* xr = x + (size_t)(rowok ? arow : 0) * D64;

    bf16x8 ahi[2], alo[2];
#pragma unroll
    for (int st = 0; st < 2; ++st) {
        float4 xa = rowok ? *(const float4*)(xr + st * 32 + kgrp)
                          : make_float4(0.f, 0.f, 0.f, 0.f);
        float4 xb = rowok ? *(const float4*)(xr + st * 32 + kgrp + 4)
                          : make_float4(0.f, 0.f, 0.f, 0.f);
        float xs[8] = {xa.x, xa.y, xa.z, xa.w, xb.x, xb.y, xb.z, xb.w};
#pragma unroll
        for (int j = 0; j < 8; ++j) {
            unsigned short h = bf16_rne(xs[j]);
            float rem = xs[j] - __uint_as_float(((uint32)h) << 16);
            ahi[st][j] = (short)h;
            alo[st][j] = (short)bf16_rne(rem);
        }
    }

    f32x4 acc[16];
#pragma unroll
    for (int t = 0; t < 16; ++t) acc[t] = f32x4{0.f, 0.f, 0.f, 0.f};

#pragma unroll
    for (int t = 0; t < 16; ++t) {
        int col = t * 16 + (lane & 15);
#pragma unroll
        for (int st = 0; st < 2; ++st) {
            int kidx = st * 32 + kgrp;
            int boff = col * 128 + ((kidx * 2) ^ ((col & 7) << 4));
            bf16x8 bhi = *(const bf16x8*)((const char*)wlds + boff);
            bf16x8 blo = *(const bf16x8*)((const char*)wlds + boff + 32768);
            acc[t] = __builtin_amdgcn_mfma_f32_16x16x32_bf16(alo[st], bhi, acc[t], 0, 0, 0);
            acc[t] = __builtin_amdgcn_mfma_f32_16x16x32_bf16(ahi[st], blo, acc[t], 0, 0, 0);
            acc[t] = __builtin_amdgcn_mfma_f32_16x16x32_bf16(ahi[st], bhi, acc[t], 0, 0, 0);
        }
    }

    int drow0 = row0 + (lane >> 4) * 4;
    int c16 = lane & 15;
#pragma unroll
    for (int t = 0; t < 4; ++t) {
        float bb = bq[t * 16 + c16];
#pragma unroll
        for (int r = 0; r < 4; ++r) {
            int row = drow0 + r;
            if (row < n) q[(size_t)row * D64 + t * 16 + c16] = acc[t][r] + bb;
        }
    }
#pragma unroll
    for (int t = 0; t < 4; ++t) {
        float bb = bs[t * 16 + c16];
#pragma unroll
        for (int r = 0; r < 4; ++r) {
            int row = drow0 + r;
            if (row < n) s[(size_t)row * D64 + t * 16 + c16] = acc[12 + t][r] + bb;
        }
    }
#pragma unroll
    for (int t = 0; t < 4; ++t) {
        float bkk = bk[t * 16 + c16];
        float bvv = bv[t * 16 + c16];
        int c = t * 16 + c16;
#pragma unroll
        for (int r = 0; r < 4; ++r) {
            int row = drow0 + r;
            float kval = acc[4 + t][r] + bkk;
            float vval = acc[8 + t][r] + bvv;
            uint32 kh = (uint32)__builtin_bit_cast(unsigned short, (_Float16)kval);
            uint32 kp = (uint32)__shfl_xor((int)kh, 1);
            uint32 kword = (lane & 1) ? (kp | (kh << 16)) : (kh | (kp << 16));
            uint32 vh = (uint32)bf16_rne(vval);
            uint32 vp = (uint32)__shfl_xor((int)vh, 1);
            uint32 vword = (lane & 1) ? (vp | (vh << 16)) : (vh | (vp << 16));
            if (row < n && !(lane & 1)) {
                uint32* rowp = (uint32*)(kv + (size_t)row * KVF);
                rowp[c >> 1] = kword;
                rowp[32 + (c >> 1)] = vword;
            }
        }
    }
}

// ---- fused edge-score + online-softmax aggregation + epilogue --------------
// Wave = 1 node; 8 groups x 8 lanes; 256B kv-row gather; fdot2 fp16 scores
// (q pre-scaled by 1/sqrt(64)); raw v_exp/v_rcp; butterfly merge.
template <int MODE>
__launch_bounds__(256)
__global__ void agg_fused(const float* __restrict__ q, const float* __restrict__ kv,
                          const int* __restrict__ csr_src,
                          const int* __restrict__ offsets,
                          const float* __restrict__ sbuf, const float* __restrict__ xin,
                          const float* __restrict__ z, float* __restrict__ out, int n) {
    int node = blockIdx.x * 4 + (threadIdx.x >> 6);
    if (node >= n) return;
    int lane = threadIdx.x & 63;
    int grp = lane >> 3, l8 = lane & 7;
    int start = offsets[node], end = offsets[node + 1];
    size_t co = (size_t)node * D64 + l8 * 8;
    float4 ta = *(const float4*)(sbuf + co);
    float4 tb = *(const float4*)(sbuf + co + 4);

    if (end > start) {
        const float4 qa = *(const float4*)(q + co);
        const float4 qb = *(const float4*)(q + co + 4);
        h2 hq0, hq1, hq2, hq3;                    // q * 0.125 folded in
        hq0[0] = (_Float16)(qa.x * 0.125f); hq0[1] = (_Float16)(qa.y * 0.125f);
        hq1[0] = (_Float16)(qa.z * 0.125f); hq1[1] = (_Float16)(qa.w * 0.125f);
        hq2[0] = (_Float16)(qb.x * 0.125f); hq2[1] = (_Float16)(qb.y * 0.125f);
        hq3[0] = (_Float16)(qb.z * 0.125f); hq3[1] = (_Float16)(qb.w * 0.125f);
        float m = -3.0e38f, den = 0.f;
        float4 aa = make_float4(0.f, 0.f, 0.f, 0.f);
        float4 ab = make_float4(0.f, 0.f, 0.f, 0.f);

        int i = start + grp;
        int idx0 = (i < end) ? i : start;
        int sj0 = csr_src[idx0];
        const float* kp0 = kv + (size_t)sj0 * KVF;
        float4 kw = *(const float4*)(kp0 + l8 * 4);
        float4 vw = *(const float4*)(kp0 + 32 + l8 * 4);

        while (i < end) {
            int inext = i + 8;
            int idx1 = (inext < end) ? inext : start;
            int sj1 = csr_src[idx1];
            const float* kp1 = kv + (size_t)sj1 * KVF;
            float4 kw1 = *(const float4*)(kp1 + l8 * 4);
            float4 vw1 = *(const float4*)(kp1 + 32 + l8 * 4);

            float p = __builtin_amdgcn_fdot2(hq0, __builtin_bit_cast(h2, kw.x),
                                             0.f, false);
            p = __builtin_amdgcn_fdot2(hq1, __builtin_bit_cast(h2, kw.y), p, false);
            p = __builtin_amdgcn_fdot2(hq2, __builtin_bit_cast(h2, kw.z), p, false);
            p = __builtin_amdgcn_fdot2(hq3, __builtin_bit_cast(h2, kw.w), p, false);
            p += __shfl_xor(p, 1, 8);
            p += __shfl_xor(p, 2, 8);
            p += __shfl_xor(p, 4, 8);
            float nm = fmaxf(m, p);
            float f  = fexp(m - nm);
            float e  = fexp(p - nm);
            den = den * f + e;
            unsigned int u0 = __float_as_uint(vw.x), u1 = __float_as_uint(vw.y);
            unsigned int u2 = __float_as_uint(vw.z), u3 = __float_as_uint(vw.w);
            float v0 = __uint_as_float(u0 << 16), v1 = __uint_as_float(u0 & 0xFFFF0000u);
            float v2 = __uint_as_float(u1 << 16), v3 = __uint_as_float(u1 & 0xFFFF0000u);
            float v4 = __uint_as_float(u2 << 16), v5 = __uint_as_float(u2 & 0xFFFF0000u);
            float v6 = __uint_as_float(u3 << 16), v7 = __uint_as_float(u3 & 0xFFFF0000u);
            aa.x = aa.x * f + e * v0; aa.y = aa.y * f + e * v1;
            aa.z = aa.z * f + e * v2; aa.w = aa.w * f + e * v3;
            ab.x = ab.x * f + e * v4; ab.y = ab.y * f + e * v5;
            ab.z = ab.z * f + e * v6; ab.w = ab.w * f + e * v7;
            m = nm;
            kw = kw1; vw = vw1;
            i = inext;
        }
        float M = fmaxf(m, __shfl_xor(m, 8));
        M = fmaxf(M, __shfl_xor(M, 16));
        M = fmaxf(M, __shfl_xor(M, 32));
        float f = fexp(m - M);
        float dd = den * f;
        dd += __shfl_xor(dd, 8); dd += __shfl_xor(dd, 16); dd += __shfl_xor(dd, 32);
        aa.x *= f; aa.y *= f; aa.z *= f; aa.w *= f;
        ab.x *= f; ab.y *= f; ab.z *= f; ab.w *= f;
        aa.x += __shfl_xor(aa.x, 8); aa.x += __shfl_xor(aa.x, 16); aa.x += __shfl_xor(aa.x, 32);
        aa.y += __shfl_xor(aa.y, 8); aa.y += __shfl_xor(aa.y, 16); aa.y += __shfl_xor(aa.y, 32);
        aa.z += __shfl_xor(aa.z, 8); aa.z += __shfl_xor(aa.z, 16); aa.z += __shfl_xor(aa.z, 32);
        aa.w += __shfl_xor(aa.w, 8); aa.w += __shfl_xor(aa.w, 16); aa.w += __shfl_xor(aa.w, 32);
        ab.x += __shfl_xor(ab.x, 8); ab.x += __shfl_xor(ab.x, 16); ab.x += __shfl_xor(ab.x, 32);
        ab.y += __shfl_xor(ab.y, 8); ab.y += __shfl_xor(ab.y, 16); ab.y += __shfl_xor(ab.y, 32);
        ab.z += __shfl_xor(ab.z, 8); ab.z += __shfl_xor(ab.z, 16); ab.z += __shfl_xor(ab.z, 32);
        ab.w += __shfl_xor(ab.w, 8); ab.w += __shfl_xor(ab.w, 16); ab.w += __shfl_xor(ab.w, 32);
        float inv = frcp(dd);
        ta.x += aa.x * inv; ta.y += aa.y * inv; ta.z += aa.z * inv; ta.w += aa.w * inv;
        tb.x += ab.x * inv; tb.y += ab.y * inv; tb.z += ab.z * inv; tb.w += ab.w * inv;
    }
    if (MODE == 1) {
        ta.x *= frcp(1.f + fexp(-ta.x)); ta.y *= frcp(1.f + fexp(-ta.y));
        ta.z *= frcp(1.f + fexp(-ta.z)); ta.w *= frcp(1.f + fexp(-ta.w));
        tb.x *= frcp(1.f + fexp(-tb.x)); tb.y *= frcp(1.f + fexp(-tb.y));
        tb.z *= frcp(1.f + fexp(-tb.z)); tb.w *= frcp(1.f + fexp(-tb.w));
    } else if (MODE == 2) {
        const float4 xa = *(const float4*)(xin + co);
        const float4 xb = *(const float4*)(xin + co + 4);
        float u;
        u = ta.x + xa.x; ta.x = u * frcp(1.f + fexp(-u));
        u = ta.y + xa.y; ta.y = u * frcp(1.f + fexp(-u));
        u = ta.z + xa.z; ta.z = u * frcp(1.f + fexp(-u));
        u = ta.w + xa.w; ta.w = u * frcp(1.f + fexp(-u));
        u = tb.x + xb.x; tb.x = u * frcp(1.f + fexp(-u));
        u = tb.y + xb.y; tb.y = u * frcp(1.f + fexp(-u));
        u = tb.z + xb.z; tb.z = u * frcp(1.f + fexp(-u));
        u = tb.w + xb.w; tb.w = u * frcp(1.f + fexp(-u));
    } else {
        const float4 za = *(const float4*)(z + co);
        const float4 zb = *(const float4*)(z + co + 4);
        ta.x += 0.1f * za.x; ta.y += 0.1f * za.y;
        ta.z += 0.1f * za.z; ta.w += 0.1f * za.w;
        tb.x += 0.1f * zb.x; tb.y += 0.1f * zb.y;
        tb.z += 0.1f * zb.z; tb.w += 0.1f * zb.w;
    }
    if (grp == 0) {
        *(float4*)(out + co) = ta;
        *(float4*)(out + co + 4) = tb;
    }
}

// ---------------------------------------------------------------------------
extern "C" void kernel_launch(void* const* d_in, const int* in_sizes, int n_in,
                              void* d_out, int out_size, void* d_ws, size_t ws_size,
                              hipStream_t stream) {
    const float* x = (const float*)d_in[0];
    const int* ei  = (const int*)d_in[1];
    const float* z = (const float*)d_in[2];
    const float* W[3][4];
    const float* B[3][4];
    for (int l = 0; l < 3; ++l)
        for (int m = 0; m < 4; ++m) {
            W[l][m] = (const float*)d_in[3 + l * 8 + m * 2];
            B[l][m] = (const float*)d_in[3 + l * 8 + m * 2 + 1];
        }
    int N = in_sizes[0] / D64;
    int E = in_sizes[1] / 2;
    size_t ND = (size_t)N * D64;

    int NB   = (N + NPB - 1) / NPB;          // buckets (391)
    int nblk = (E + CHUNK - 1) / CHUNK;      // edge chunks (196)
    int nscan = NB * nblk;                   // ~77k
    int nb2  = (nscan + 1023) / 1024;        // scan blocks (~75)

    char* p = (char*)d_ws;
    auto alloc = [&](size_t bytes) {
        char* r = p;
        p += (bytes + 255) & ~(size_t)255;
        return r;
    };
    float* q       = (float*)alloc(ND * 4);
    float* kv      = (float*)alloc((size_t)N * KVF * 4);
    float* sb      = (float*)alloc(ND * 4);
    float* hA      = (float*)alloc(ND * 4);
    int* csr_src   = (int*)alloc((size_t)E * 4);
    uint32* pc     = (uint32*)alloc((size_t)E * 4);
    uint32* pairs  = (uint32*)alloc((size_t)E * 4);
    int* offsets   = (int*)alloc((size_t)(N + 1) * 4);
    int* bhT       = (int*)alloc((size_t)nscan * 4);
    int* partial   = (int*)alloc((size_t)nscan * 4);
    int* ebase     = (int*)alloc((size_t)nscan * 4);
    int* blockSums = (int*)alloc((size_t)nb2 * 4);
    uint32* wpack  = (uint32*)alloc(3 * 16384 * 4);
    int* flag      = (int*)alloc(4);
    float* outp    = (float*)d_out;

    hipMemsetAsync(flag, 0, 4, stream);
    int nchecks = E < 4096 ? E : 4096;
    detect_fmt<<<1, 256, 0, stream>>>(ei, nchecks, flag);
    prep_w<<<12, 256, 0, stream>>>(W[0][0], W[0][1], W[0][2], W[0][3],
                                   W[1][0], W[1][1], W[1][2], W[1][3],
                                   W[2][0], W[2][1], W[2][2], W[2][3], wpack);
    hist_pack<<<nblk, 256, 0, stream>>>(ei, bhT, pc, E, nblk, NB, flag);
    scan_blocks<<<nb2, 256, 0, stream>>>(bhT, partial, blockSums, nscan);
    scan_sums<<<1, 64, 0, stream>>>(blockSums, nb2);
    make_excl<<<(nscan + 255) / 256, 256, 0, stream>>>(bhT, partial, blockSums,
                                                       ebase, nscan);
    bucket_scatter<<<nblk, 256, 0, stream>>>(pc, ebase, pairs, E, nblk, NB);
    bucket_finalize<<<NB, 256, 0, stream>>>(pairs, ebase, nblk, NB,
                                            csr_src, offsets, N, E);

    int gemm_grid = (N + 63) / 64;
    int node_grid = (N + 3) / 4;

    // layer 1: x -> hA, silu
    gemm_mfma<<<gemm_grid, 256, 0, stream>>>(x, wpack, B[0][0], B[0][1],
                                             B[0][2], B[0][3], q, kv, sb, N);
    agg_fused<1><<<node_grid, 256, 0, stream>>>(q, kv, csr_src, offsets, sb,
                                                nullptr, nullptr, hA, N);
    // layer 2: hA -> hA (residual + silu)
    gemm_mfma<<<gemm_grid, 256, 0, stream>>>(hA, wpack + 16384, B[1][0], B[1][1],
                                             B[1][2], B[1][3], q, kv, sb, N);
    agg_fused<2><<<node_grid, 256, 0, stream>>>(q, kv, csr_src, offsets, sb,
                                                hA, nullptr, hA, N);
    // layer 3: hA -> out, + 0.1*z
    gemm_mfma<<<gemm_grid, 256, 0, stream>>>(hA, wpack + 32768, B[2][0], B[2][1],
                                             B[2][2], B[2][3], q, kv, sb, N);
    agg_fused<3><<<node_grid, 256, 0, stream>>>(q, kv, csr_src, offsets, sb,
                                                nullptr, z, outp, N);
}

// Round 12
// 217.405 us; speedup vs baseline: 3.0569x; 1.0821x over previous
//
#include <hip/hip_runtime.h>
#include <math.h>

// ---------------------------------------------------------------------------
// PseqStepV3: 3-layer TransformerConv (heads=1), N=50000, E=800000, D=64.
//   setup: detect edge dtype; atomic-free bucketed CSR build (packed 32-bit
//          src|dst words); prep_w packs W into bf16 hi/lo, swizzled.
//   per layer: MFMA q/kv/s GEMM (16x16x32 bf16 hi/lo split; two-stage 32KB
//              LDS for 2x occupancy; q/sb streamed as fp16, q pre-scaled)
//              -> fused online-softmax aggregation (256B kv-row gather,
//                 fdot2 fp16 scores, raw v_exp/v_rcp; fp16 hA stream)
// ---------------------------------------------------------------------------

#define D64 64
#define KVF 64       // floats per kv row: 32 words fp16 k + 32 words bf16 v
#define NPB 128      // nodes per bucket (pow2 -> bucket = dst >> 7)
#define MAXNB 512    // LDS sizing bound for bucket count (N <= 65536)
#define CHUNK 4096   // edges per block in bucket passes

typedef _Float16 h2 __attribute__((ext_vector_type(2)));
typedef __attribute__((ext_vector_type(8))) short bf16x8;
typedef __attribute__((ext_vector_type(4))) float f32x4;
typedef unsigned int uint32;
typedef unsigned short ushort16;

__device__ __forceinline__ unsigned short bf16_rne(float f) {
    unsigned int u = __float_as_uint(f);
    u += 0x7FFFu + ((u >> 16) & 1u);
    return (unsigned short)(u >> 16);
}
__device__ __forceinline__ float fexp(float x) {
    return __builtin_amdgcn_exp2f(x * 1.44269504089f);
}
__device__ __forceinline__ float frcp(float x) {
    return __builtin_amdgcn_rcpf(x);
}
__device__ __forceinline__ uint32 pack2h(float a, float b) {
    uint32 ua = (uint32)__builtin_bit_cast(unsigned short, (_Float16)a);
    uint32 ub = (uint32)__builtin_bit_cast(unsigned short, (_Float16)b);
    return ua | (ub << 16);
}
__device__ __forceinline__ float2 unpack2h(uint32 w) {
    h2 h = __builtin_bit_cast(h2, w);
    return make_float2((float)h[0], (float)h[1]);
}

// ---- edge_index format detection: int64 rows have zero high words ----------
__global__ void detect_fmt(const int* __restrict__ ei, int nchecks, int* flag) {
    int t = blockIdx.x * blockDim.x + threadIdx.x;
    int acc = 0;
    for (int i = t; i < nchecks; i += blockDim.x * gridDim.x)
        acc |= ei[2 * i + 1];
    if (acc) atomicOr(flag, 1);   // nonzero => plain int32 layout
}

__device__ __forceinline__ int load_src(const int* ei, int e, int E, int is64) {
    return is64 ? ei[2 * e] : ei[e];
}
__device__ __forceinline__ int load_dst(const int* ei, int e, int E, int is64) {
    return is64 ? ei[2 * E + 2 * e] : ei[E + e];
}

// ---- CSR build: bucketed, atomic-free (LDS atomics only) -------------------
__global__ void hist_pack(const int* __restrict__ ei, int* __restrict__ bhT,
                          uint32* __restrict__ pc, int E, int nblk, int NB,
                          const int* __restrict__ flag) {
    __shared__ int h[MAXNB];
    int blk = blockIdx.x, tid = threadIdx.x;
    for (int i = tid; i < NB; i += 256) h[i] = 0;
    __syncthreads();
    int is64 = (*flag == 0);
    int e1 = blk * CHUNK + CHUNK; if (e1 > E) e1 = E;
    for (int e = blk * CHUNK + tid; e < e1; e += 256) {
        int s = load_src(ei, e, E, is64);
        int d = load_dst(ei, e, E, is64);
        pc[e] = (uint32)s | ((uint32)d << 16);
        atomicAdd(&h[d >> 7], 1);
    }
    __syncthreads();
    for (int i = tid; i < NB; i += 256) bhT[i * nblk + blk] = h[i];
}

__global__ void scan_blocks(const int* __restrict__ counts, int* __restrict__ partial,
                            int* __restrict__ blockSums, int n) {
    int tid = threadIdx.x;                 // 256
    int base = blockIdx.x * 1024 + tid * 4;
    int4 c = make_int4(0, 0, 0, 0);
    if (base + 3 < n) c = *(const int4*)&counts[base];
    else {
        if (base + 0 < n) c.x = counts[base + 0];
        if (base + 1 < n) c.y = counts[base + 1];
        if (base + 2 < n) c.z = counts[base + 2];
        if (base + 3 < n) c.w = counts[base + 3];
    }
    int s1 = c.x, s2 = s1 + c.y, s3 = s2 + c.z, s4 = s3 + c.w;
    int lane = tid & 63, wave = tid >> 6;
    int v = s4;
#pragma unroll
    for (int off = 1; off < 64; off <<= 1) {
        int t = __shfl_up(v, off);
        if (lane >= off) v += t;
    }
    __shared__ int wsum[4];
    if (lane == 63) wsum[wave] = v;
    __syncthreads();
    int wpre = 0;
    for (int w = 0; w < wave; ++w) wpre += wsum[w];
    int pre = wpre + v - s4;
    if (base + 0 < n) partial[base + 0] = pre + s1;
    if (base + 1 < n) partial[base + 1] = pre + s2;
    if (base + 2 < n) partial[base + 2] = pre + s3;
    if (base + 3 < n) partial[base + 3] = pre + s4;
    if (tid == 255) blockSums[blockIdx.x] = wsum[0] + wsum[1] + wsum[2] + wsum[3];
}

__global__ void scan_sums(int* __restrict__ bs, int nb) {
    int lane = threadIdx.x;                // 64
    int carry = 0;
    for (int b0 = 0; b0 < nb; b0 += 64) {
        int i = b0 + lane;
        int val = (i < nb) ? bs[i] : 0;
        int v = val;
#pragma unroll
        for (int off = 1; off < 64; off <<= 1) {
            int t = __shfl_up(v, off);
            if (lane >= off) v += t;
        }
        if (i < nb) bs[i] = carry + v - val;   // exclusive
        carry += __shfl(v, 63);
    }
}

__global__ void make_excl(const int* __restrict__ bh, const int* __restrict__ partial,
                          const int* __restrict__ bs, int* __restrict__ ebase, int n) {
    int i = blockIdx.x * 256 + threadIdx.x;
    if (i >= n) return;
    ebase[i] = partial[i] + bs[i >> 10] - bh[i];   // exclusive global scan
}

__global__ void bucket_scatter(const uint32* __restrict__ pc, const int* __restrict__ ebase,
                               uint32* __restrict__ pairs, int E, int nblk, int NB) {
    __shared__ int cur[MAXNB];
    int blk = blockIdx.x, tid = threadIdx.x;
    for (int i = tid; i < NB; i += 256) cur[i] = ebase[i * nblk + blk];
    __syncthreads();
    int e1 = blk * CHUNK + CHUNK; if (e1 > E) e1 = E;
    for (int e = blk * CHUNK + tid; e < e1; e += 256) {
        uint32 w = pc[e];
        int pos = atomicAdd(&cur[w >> 23], 1);   // bucket = dst >> 7
        pairs[pos] = w;
    }
}

__global__ void bucket_finalize(const uint32* __restrict__ pairs,
                                const int* __restrict__ ebase, int nblk, int NB,
                                int* __restrict__ csr_src, int* __restrict__ offsets,
                                int N, int E) {
    __shared__ int hist[NPB];
    __shared__ int cur[NPB];
    int b = blockIdx.x, tid = threadIdx.x;
    int n0 = b * NPB;
    int cnt = N - n0; if (cnt > NPB) cnt = NPB;
    if (cnt <= 0) return;
    int estart = ebase[b * nblk];
    int eend = (b + 1 < NB) ? ebase[(b + 1) * nblk] : E;
    for (int i = tid; i < cnt; i += 256) hist[i] = 0;
    __syncthreads();
    for (int e = estart + tid; e < eend; e += 256)
        atomicAdd(&hist[(int)(pairs[e] >> 16) - n0], 1);
    __syncthreads();
    if (tid == 0) {
        int run = estart;
        for (int i = 0; i < cnt; ++i) {
            cur[i] = run;
            offsets[n0 + i] = run;
            run += hist[i];
        }
    }
    if (b == 0 && tid == 1) offsets[N] = E;
    __syncthreads();
    for (int e = estart + tid; e < eend; e += 256) {
        uint32 w = pairs[e];
        int pos = atomicAdd(&cur[(int)(w >> 16) - n0], 1);
        csr_src[pos] = (int)(w & 0xFFFFu);
    }
}

// ---- W prep: bf16 hi/lo split, [col][k] layout, XOR-swizzled ---------------
__global__ void prep_w(const float* W0, const float* W1, const float* W2,
                       const float* W3, const float* W4, const float* W5,
                       const float* W6, const float* W7, const float* W8,
                       const float* W9, const float* W10, const float* W11,
                       uint32* __restrict__ wpack) {
    const float* Wm;
    switch (blockIdx.x) {
        case 0: Wm = W0; break;  case 1: Wm = W1; break;
        case 2: Wm = W2; break;  case 3: Wm = W3; break;
        case 4: Wm = W4; break;  case 5: Wm = W5; break;
        case 6: Wm = W6; break;  case 7: Wm = W7; break;
        case 8: Wm = W8; break;  case 9: Wm = W9; break;
        case 10: Wm = W10; break; default: Wm = W11; break;
    }
    int layer = blockIdx.x >> 2, mat = blockIdx.x & 3;
    uint32* hiB = wpack + layer * 16384;
    uint32* loB = hiB + 8192;
    int d = threadIdx.x & 63;
    int cg = threadIdx.x >> 6;
    int col = mat * 64 + d;
    for (int kw = cg; kw < 32; kw += 4) {
        float w0 = Wm[(2 * kw) * 64 + d];
        float w1 = Wm[(2 * kw + 1) * 64 + d];
        unsigned short h0 = bf16_rne(w0);
        unsigned short h1 = bf16_rne(w1);
        float r0 = w0 - __uint_as_float(((uint32)h0) << 16);
        float r1 = w1 - __uint_as_float(((uint32)h1) << 16);
        unsigned short l0 = bf16_rne(r0);
        unsigned short l1 = bf16_rne(r1);
        int sw = ((kw * 4) ^ ((col & 7) << 4)) >> 2;
        hiB[col * 32 + sw] = (uint32)h0 | ((uint32)h1 << 16);
        loB[col * 32 + sw] = (uint32)l0 | ((uint32)l1 << 16);
    }
}

// ---- MFMA q/kv/s GEMM ------------------------------------------------------
// Two-stage 32KB LDS (hi weights -> alo*bhi + ahi*bhi; lo weights -> ahi*blo)
// for 4-5 blocks/CU (was 2 at 64KB). IN16: x rows are fp16 (hA stream).
// Outputs: q fp16 PRE-SCALED by 1/sqrt(64), s fp16, kv row (fp16 k | bf16 v).
template <int IN16>
__launch_bounds__(256)
__global__ void gemm_mfma(const void* __restrict__ xv, const uint32* __restrict__ wpackL,
                          const float* __restrict__ bq, const float* __restrict__ bk,
                          const float* __restrict__ bv, const float* __restrict__ bs,
                          ushort16* __restrict__ qh, float* __restrict__ kv,
                          ushort16* __restrict__ sh, int n) {
    __shared__ uint32 wlds[8192];   // 32 KiB, one hi/lo stage at a time
    int tid = threadIdx.x;
    int lane = tid & 63, wave = tid >> 6;
    int row0 = blockIdx.x * 64 + wave * 16;
    int arow = row0 + (lane & 15);
    int kgrp = (lane >> 4) * 8;
    bool rowok = arow < n;

    bf16x8 ahi[2], alo[2];
#pragma unroll
    for (int st = 0; st < 2; ++st) {
        float xs[8];
        if (IN16) {
            const ushort16* xr = (const ushort16*)xv + (size_t)(rowok ? arow : 0) * D64;
            uint4 xw = rowok ? *(const uint4*)(xr + st * 32 + kgrp)
                             : make_uint4(0, 0, 0, 0);
            float2 p0 = unpack2h(xw.x), p1 = unpack2h(xw.y);
            float2 p2 = unpack2h(xw.z), p3 = unpack2h(xw.w);
            xs[0] = p0.x; xs[1] = p0.y; xs[2] = p1.x; xs[3] = p1.y;
            xs[4] = p2.x; xs[5] = p2.y; xs[6] = p3.x; xs[7] = p3.y;
        } else {
            const float* xr = (const float*)xv + (size_t)(rowok ? arow : 0) * D64;
            float4 xa = rowok ? *(const float4*)(xr + st * 32 + kgrp)
                              : make_float4(0.f, 0.f, 0.f, 0.f);
            float4 xb = rowok ? *(const float4*)(xr + st * 32 + kgrp + 4)
                              : make_float4(0.f, 0.f, 0.f, 0.f);
            xs[0] = xa.x; xs[1] = xa.y; xs[2] = xa.z; xs[3] = xa.w;
            xs[4] = xb.x; xs[5] = xb.y; xs[6] = xb.z; xs[7] = xb.w;
        }
#pragma unroll
        for (int j = 0; j < 8; ++j) {
            unsigned short h = bf16_rne(xs[j]);
            float rem = xs[j] - __uint_as_float(((uint32)h) << 16);
            ahi[st][j] = (short)h;
            alo[st][j] = (short)bf16_rne(rem);
        }
    }

    f32x4 acc[16];
#pragma unroll
    for (int t = 0; t < 16; ++t) acc[t] = f32x4{0.f, 0.f, 0.f, 0.f};

    // stage 1: hi weights -> alo*bhi + ahi*bhi
#pragma unroll
    for (int r = 0; r < 8; ++r) {
        int w4 = r * 1024 + tid * 4;
        *(uint4*)&wlds[w4] = *(const uint4*)&wpackL[w4];
    }
    __syncthreads();
#pragma unroll
    for (int t = 0; t < 16; ++t) {
        int col = t * 16 + (lane & 15);
#pragma unroll
        for (int st = 0; st < 2; ++st) {
            int kidx = st * 32 + kgrp;
            int boff = col * 128 + ((kidx * 2) ^ ((col & 7) << 4));
            bf16x8 bhi = *(const bf16x8*)((const char*)wlds + boff);
            acc[t] = __builtin_amdgcn_mfma_f32_16x16x32_bf16(alo[st], bhi, acc[t], 0, 0, 0);
            acc[t] = __builtin_amdgcn_mfma_f32_16x16x32_bf16(ahi[st], bhi, acc[t], 0, 0, 0);
        }
    }
    __syncthreads();
    // stage 2: lo weights -> ahi*blo
#pragma unroll
    for (int r = 0; r < 8; ++r) {
        int w4 = r * 1024 + tid * 4;
        *(uint4*)&wlds[w4] = *(const uint4*)&wpackL[8192 + w4];
    }
    __syncthreads();
#pragma unroll
    for (int t = 0; t < 16; ++t) {
        int col = t * 16 + (lane & 15);
#pragma unroll
        for (int st = 0; st < 2; ++st) {
            int kidx = st * 32 + kgrp;
            int boff = col * 128 + ((kidx * 2) ^ ((col & 7) << 4));
            bf16x8 blo = *(const bf16x8*)((const char*)wlds + boff);
            acc[t] = __builtin_amdgcn_mfma_f32_16x16x32_bf16(ahi[st], blo, acc[t], 0, 0, 0);
        }
    }

    int drow0 = row0 + (lane >> 4) * 4;
    int c16 = lane & 15;
    // q tiles 0-3 (fp16, pre-scaled by 0.125) + s tiles 12-15 (fp16)
#pragma unroll
    for (int t = 0; t < 4; ++t) {
        float bbq = bq[t * 16 + c16];
        float bbs = bs[t * 16 + c16];
        int c = t * 16 + c16;
#pragma unroll
        for (int r = 0; r < 4; ++r) {
            int row = drow0 + r;
            float qval = (acc[t][r] + bbq) * 0.125f;
            float sval = acc[12 + t][r] + bbs;
            uint32 qu = (uint32)__builtin_bit_cast(unsigned short, (_Float16)qval);
            uint32 qp = (uint32)__shfl_xor((int)qu, 1);
            uint32 qword = (lane & 1) ? (qp | (qu << 16)) : (qu | (qp << 16));
            uint32 su = (uint32)__builtin_bit_cast(unsigned short, (_Float16)sval);
            uint32 sp = (uint32)__shfl_xor((int)su, 1);
            uint32 sword = (lane & 1) ? (sp | (su << 16)) : (su | (sp << 16));
            if (row < n && !(lane & 1)) {
                ((uint32*)(qh + (size_t)row * D64))[c >> 1] = qword;
                ((uint32*)(sh + (size_t)row * D64))[c >> 1] = sword;
            }
        }
    }
    // k tiles 4-7 (fp16, kv words 0-31) + v tiles 8-11 (bf16, kv words 32-63)
#pragma unroll
    for (int t = 0; t < 4; ++t) {
        float bkk = bk[t * 16 + c16];
        float bvv = bv[t * 16 + c16];
        int c = t * 16 + c16;
#pragma unroll
        for (int r = 0; r < 4; ++r) {
            int row = drow0 + r;
            float kval = acc[4 + t][r] + bkk;
            float vval = acc[8 + t][r] + bvv;
            uint32 kh = (uint32)__builtin_bit_cast(unsigned short, (_Float16)kval);
            uint32 kp = (uint32)__shfl_xor((int)kh, 1);
            uint32 kword = (lane & 1) ? (kp | (kh << 16)) : (kh | (kp << 16));
            uint32 vh = (uint32)bf16_rne(vval);
            uint32 vp = (uint32)__shfl_xor((int)vh, 1);
            uint32 vword = (lane & 1) ? (vp | (vh << 16)) : (vh | (vp << 16));
            if (row < n && !(lane & 1)) {
                uint32* rowp = (uint32*)(kv + (size_t)row * KVF);
                rowp[c >> 1] = kword;
                rowp[32 + (c >> 1)] = vword;
            }
        }
    }
}

// ---- fused edge-score + online-softmax aggregation + epilogue --------------
// Wave = 1 node; 8 groups x 8 lanes; 256B kv-row gather; fdot2 fp16 scores
// (q pre-scaled at gemm); raw v_exp/v_rcp; butterfly merge.
// MODE 1: outh = silu(t) fp16   MODE 2: outh = silu(t + xin) fp16 (in-place)
// MODE 3: outf = t + 0.1*z fp32
template <int MODE>
__launch_bounds__(256)
__global__ void agg_fused(const ushort16* __restrict__ qh, const float* __restrict__ kv,
                          const int* __restrict__ csr_src,
                          const int* __restrict__ offsets,
                          const ushort16* __restrict__ sbh, const ushort16* __restrict__ xinh,
                          const float* __restrict__ z, void* __restrict__ outp, int n) {
    int node = blockIdx.x * 4 + (threadIdx.x >> 6);
    if (node >= n) return;
    int lane = threadIdx.x & 63;
    int grp = lane >> 3, l8 = lane & 7;
    int start = offsets[node], end = offsets[node + 1];
    size_t co2 = (size_t)node * D64 + l8 * 8;   // halfword index
    uint4 sw = *(const uint4*)(sbh + co2);
    float2 s0 = unpack2h(sw.x), s1 = unpack2h(sw.y);
    float2 s2 = unpack2h(sw.z), s3 = unpack2h(sw.w);
    float4 ta = make_float4(s0.x, s0.y, s1.x, s1.y);
    float4 tb = make_float4(s2.x, s2.y, s3.x, s3.y);

    if (end > start) {
        uint4 qw = *(const uint4*)(qh + co2);
        h2 hq0 = __builtin_bit_cast(h2, qw.x);
        h2 hq1 = __builtin_bit_cast(h2, qw.y);
        h2 hq2 = __builtin_bit_cast(h2, qw.z);
        h2 hq3 = __builtin_bit_cast(h2, qw.w);
        float m = -3.0e38f, den = 0.f;
        float4 aa = make_float4(0.f, 0.f, 0.f, 0.f);
        float4 ab = make_float4(0.f, 0.f, 0.f, 0.f);

        int i = start + grp;
        int idx0 = (i < end) ? i : start;
        int sj0 = csr_src[idx0];
        const float* kp0 = kv + (size_t)sj0 * KVF;
        float4 kw = *(const float4*)(kp0 + l8 * 4);
        float4 vw = *(const float4*)(kp0 + 32 + l8 * 4);

        while (i < end) {
            int inext = i + 8;
            int idx1 = (inext < end) ? inext : start;
            int sj1 = csr_src[idx1];
            const float* kp1 = kv + (size_t)sj1 * KVF;
            float4 kw1 = *(const float4*)(kp1 + l8 * 4);
            float4 vw1 = *(const float4*)(kp1 + 32 + l8 * 4);

            float p = __builtin_amdgcn_fdot2(hq0, __builtin_bit_cast(h2, kw.x),
                                             0.f, false);
            p = __builtin_amdgcn_fdot2(hq1, __builtin_bit_cast(h2, kw.y), p, false);
            p = __builtin_amdgcn_fdot2(hq2, __builtin_bit_cast(h2, kw.z), p, false);
            p = __builtin_amdgcn_fdot2(hq3, __builtin_bit_cast(h2, kw.w), p, false);
            p += __shfl_xor(p, 1, 8);
            p += __shfl_xor(p, 2, 8);
            p += __shfl_xor(p, 4, 8);
            float nm = fmaxf(m, p);
            float f  = fexp(m - nm);
            float e  = fexp(p - nm);
            den = den * f + e;
            unsigned int u0 = __float_as_uint(vw.x), u1 = __float_as_uint(vw.y);
            unsigned int u2 = __float_as_uint(vw.z), u3 = __float_as_uint(vw.w);
            float v0 = __uint_as_float(u0 << 16), v1 = __uint_as_float(u0 & 0xFFFF0000u);
            float v2 = __uint_as_float(u1 << 16), v3 = __uint_as_float(u1 & 0xFFFF0000u);
            float v4 = __uint_as_float(u2 << 16), v5 = __uint_as_float(u2 & 0xFFFF0000u);
            float v6 = __uint_as_float(u3 << 16), v7 = __uint_as_float(u3 & 0xFFFF0000u);
            aa.x = aa.x * f + e * v0; aa.y = aa.y * f + e * v1;
            aa.z = aa.z * f + e * v2; aa.w = aa.w * f + e * v3;
            ab.x = ab.x * f + e * v4; ab.y = ab.y * f + e * v5;
            ab.z = ab.z * f + e * v6; ab.w = ab.w * f + e * v7;
            m = nm;
            kw = kw1; vw = vw1;
            i = inext;
        }
        float M = fmaxf(m, __shfl_xor(m, 8));
        M = fmaxf(M, __shfl_xor(M, 16));
        M = fmaxf(M, __shfl_xor(M, 32));
        float f = fexp(m - M);
        float dd = den * f;
        dd += __shfl_xor(dd, 8); dd += __shfl_xor(dd, 16); dd += __shfl_xor(dd, 32);
        aa.x *= f; aa.y *= f; aa.z *= f; aa.w *= f;
        ab.x *= f; ab.y *= f; ab.z *= f; ab.w *= f;
        aa.x += __shfl_xor(aa.x, 8); aa.x += __shfl_xor(aa.x, 16); aa.x += __shfl_xor(aa.x, 32);
        aa.y += __shfl_xor(aa.y, 8); aa.y += __shfl_xor(aa.y, 16); aa.y += __shfl_xor(aa.y, 32);
        aa.z += __shfl_xor(aa.z, 8); aa.z += __shfl_xor(aa.z, 16); aa.z += __shfl_xor(aa.z, 32);
        aa.w += __shfl_xor(aa.w, 8); aa.w += __shfl_xor(aa.w, 16); aa.w += __shfl_xor(aa.w, 32);
        ab.x += __shfl_xor(ab.x, 8); ab.x += __shfl_xor(ab.x, 16); ab.x += __shfl_xor(ab.x, 32);
        ab.y += __shfl_xor(ab.y, 8); ab.y += __shfl_xor(ab.y, 16); ab.y += __shfl_xor(ab.y, 32);
        ab.z += __shfl_xor(ab.z, 8); ab.z += __shfl_xor(ab.z, 16); ab.z += __shfl_xor(ab.z, 32);
        ab.w += __shfl_xor(ab.w, 8); ab.w += __shfl_xor(ab.w, 16); ab.w += __shfl_xor(ab.w, 32);
        float inv = frcp(dd);
        ta.x += aa.x * inv; ta.y += aa.y * inv; ta.z += aa.z * inv; ta.w += aa.w * inv;
        tb.x += ab.x * inv; tb.y += ab.y * inv; tb.z += ab.z * inv; tb.w += ab.w * inv;
    }
    if (MODE == 1) {
        ta.x *= frcp(1.f + fexp(-ta.x)); ta.y *= frcp(1.f + fexp(-ta.y));
        ta.z *= frcp(1.f + fexp(-ta.z)); ta.w *= frcp(1.f + fexp(-ta.w));
        tb.x *= frcp(1.f + fexp(-tb.x)); tb.y *= frcp(1.f + fexp(-tb.y));
        tb.z *= frcp(1.f + fexp(-tb.z)); tb.w *= frcp(1.f + fexp(-tb.w));
    } else if (MODE == 2) {
        uint4 xw = *(const uint4*)(xinh + co2);
        float2 x0 = unpack2h(xw.x), x1 = unpack2h(xw.y);
        float2 x2 = unpack2h(xw.z), x3 = unpack2h(xw.w);
        float u;
        u = ta.x + x0.x; ta.x = u * frcp(1.f + fexp(-u));
        u = ta.y + x0.y; ta.y = u * frcp(1.f + fexp(-u));
        u = ta.z + x1.x; ta.z = u * frcp(1.f + fexp(-u));
        u = ta.w + x1.y; ta.w = u * frcp(1.f + fexp(-u));
        u = tb.x + x2.x; tb.x = u * frcp(1.f + fexp(-u));
        u = tb.y + x2.y; tb.y = u * frcp(1.f + fexp(-u));
        u = tb.z + x3.x; tb.z = u * frcp(1.f + fexp(-u));
        u = tb.w + x3.y; tb.w = u * frcp(1.f + fexp(-u));
    } else {
        size_t cof = (size_t)node * D64 + l8 * 8;
        const float4 za = *(const float4*)(z + cof);
        const float4 zb = *(const float4*)(z + cof + 4);
        ta.x += 0.1f * za.x; ta.y += 0.1f * za.y;
        ta.z += 0.1f * za.z; ta.w += 0.1f * za.w;
        tb.x += 0.1f * zb.x; tb.y += 0.1f * zb.y;
        tb.z += 0.1f * zb.z; tb.w += 0.1f * zb.w;
    }
    if (grp == 0) {
        if (MODE == 3) {
            float* outf = (float*)outp;
            size_t cof = (size_t)node * D64 + l8 * 8;
            *(float4*)(outf + cof) = ta;
            *(float4*)(outf + cof + 4) = tb;
        } else {
            ushort16* outh = (ushort16*)outp;
            uint4 ow;
            ow.x = pack2h(ta.x, ta.y); ow.y = pack2h(ta.z, ta.w);
            ow.z = pack2h(tb.x, tb.y); ow.w = pack2h(tb.z, tb.w);
            *(uint4*)(outh + co2) = ow;
        }
    }
}

// ---------------------------------------------------------------------------
extern "C" void kernel_launch(void* const* d_in, const int* in_sizes, int n_in,
                              void* d_out, int out_size, void* d_ws, size_t ws_size,
                              hipStream_t stream) {
    const float* x = (const float*)d_in[0];
    const int* ei  = (const int*)d_in[1];
    const float* z = (const float*)d_in[2];
    const float* W[3][4];
    const float* B[3][4];
    for (int l = 0; l < 3; ++l)
        for (int m = 0; m < 4; ++m) {
            W[l][m] = (const float*)d_in[3 + l * 8 + m * 2];
            B[l][m] = (const float*)d_in[3 + l * 8 + m * 2 + 1];
        }
    int N = in_sizes[0] / D64;
    int E = in_sizes[1] / 2;
    size_t ND = (size_t)N * D64;

    int NB   = (N + NPB - 1) / NPB;          // buckets (391)
    int nblk = (E + CHUNK - 1) / CHUNK;      // edge chunks (196)
    int nscan = NB * nblk;                   // ~77k
    int nb2  = (nscan + 1023) / 1024;        // scan blocks (~75)

    char* p = (char*)d_ws;
    auto alloc = [&](size_t bytes) {
        char* r = p;
        p += (bytes + 255) & ~(size_t)255;
        return r;
    };
    ushort16* qh   = (ushort16*)alloc(ND * 2);
    ushort16* sbh  = (ushort16*)alloc(ND * 2);
    ushort16* hAh  = (ushort16*)alloc(ND * 2);
    float* kv      = (float*)alloc((size_t)N * KVF * 4);
    int* csr_src   = (int*)alloc((size_t)E * 4);
    uint32* pc     = (uint32*)alloc((size_t)E * 4);
    uint32* pairs  = (uint32*)alloc((size_t)E * 4);
    int* offsets   = (int*)alloc((size_t)(N + 1) * 4);
    int* bhT       = (int*)alloc((size_t)nscan * 4);
    int* partial   = (int*)alloc((size_t)nscan * 4);
    int* ebase     = (int*)alloc((size_t)nscan * 4);
    int* blockSums = (int*)alloc((size_t)nb2 * 4);
    uint32* wpack  = (uint32*)alloc(3 * 16384 * 4);
    int* flag      = (int*)alloc(4);
    float* outp    = (float*)d_out;

    hipMemsetAsync(flag, 0, 4, stream);
    int nchecks = E < 4096 ? E : 4096;
    detect_fmt<<<1, 256, 0, stream>>>(ei, nchecks, flag);
    prep_w<<<12, 256, 0, stream>>>(W[0][0], W[0][1], W[0][2], W[0][3],
                                   W[1][0], W[1][1], W[1][2], W[1][3],
                                   W[2][0], W[2][1], W[2][2], W[2][3], wpack);
    hist_pack<<<nblk, 256, 0, stream>>>(ei, bhT, pc, E, nblk, NB, flag);
    scan_blocks<<<nb2, 256, 0, stream>>>(bhT, partial, blockSums, nscan);
    scan_sums<<<1, 64, 0, stream>>>(blockSums, nb2);
    make_excl<<<(nscan + 255) / 256, 256, 0, stream>>>(bhT, partial, blockSums,
                                                       ebase, nscan);
    bucket_scatter<<<nblk, 256, 0, stream>>>(pc, ebase, pairs, E, nblk, NB);
    bucket_finalize<<<NB, 256, 0, stream>>>(pairs, ebase, nblk, NB,
                                            csr_src, offsets, N, E);

    int gemm_grid = (N + 63) / 64;
    int node_grid = (N + 3) / 4;

    // layer 1: x (fp32) -> hAh (fp16), silu
    gemm_mfma<0><<<gemm_grid, 256, 0, stream>>>(x, wpack, B[0][0], B[0][1],
                                                B[0][2], B[0][3], qh, kv, sbh, N);
    agg_fused<1><<<node_grid, 256, 0, stream>>>(qh, kv, csr_src, offsets, sbh,
                                                nullptr, nullptr, hAh, N);
    // layer 2: hAh -> hAh (residual + silu, in-place)
    gemm_mfma<1><<<gemm_grid, 256, 0, stream>>>(hAh, wpack + 16384, B[1][0], B[1][1],
                                                B[1][2], B[1][3], qh, kv, sbh, N);
    agg_fused<2><<<node_grid, 256, 0, stream>>>(qh, kv, csr_src, offsets, sbh,
                                                hAh, nullptr, hAh, N);
    // layer 3: hAh -> out (fp32), + 0.1*z
    gemm_mfma<1><<<gemm_grid, 256, 0, stream>>>(hAh, wpack + 32768, B[2][0], B[2][1],
                                                B[2][2], B[2][3], qh, kv, sbh, N);
    agg_fused<3><<<node_grid, 256, 0, stream>>>(qh, kv, csr_src, offsets, sbh,
                                                nullptr, z, outp, N);
}

// Round 13
// 207.222 us; speedup vs baseline: 3.2071x; 1.0491x over previous
//
#include <hip/hip_runtime.h>
#include <math.h>

// ---------------------------------------------------------------------------
// PseqStepV3: 3-layer TransformerConv (heads=1), N=50000, E=800000, D=64.
//   setup: detect edge dtype; atomic-free bucketed CSR build (packed 32-bit
//          src|dst words); prep_w packs W into bf16 hi/lo, swizzled.
//   per layer: MFMA q/kv/s GEMM (16x16x32 bf16 hi/lo split; two-stage 32KB
//              LDS; LDS-transposed coalesced epilogue, R13)
//              -> fused online-softmax aggregation (256B kv-row gather,
//                 fdot2 fp16 scores, raw v_exp/v_rcp; fp16 hA stream)
// ---------------------------------------------------------------------------

#define D64 64
#define KVF 64       // floats per kv row: 32 words fp16 k + 32 words bf16 v
#define NPB 128      // nodes per bucket (pow2 -> bucket = dst >> 7)
#define MAXNB 512    // LDS sizing bound for bucket count (N <= 65536)
#define CHUNK 4096   // edges per block in bucket passes

typedef _Float16 h2 __attribute__((ext_vector_type(2)));
typedef __attribute__((ext_vector_type(8))) short bf16x8;
typedef __attribute__((ext_vector_type(4))) float f32x4;
typedef unsigned int uint32;
typedef unsigned short ushort16;

__device__ __forceinline__ unsigned short bf16_rne(float f) {
    unsigned int u = __float_as_uint(f);
    u += 0x7FFFu + ((u >> 16) & 1u);
    return (unsigned short)(u >> 16);
}
__device__ __forceinline__ float fexp(float x) {
    return __builtin_amdgcn_exp2f(x * 1.44269504089f);
}
__device__ __forceinline__ float frcp(float x) {
    return __builtin_amdgcn_rcpf(x);
}
__device__ __forceinline__ uint32 pack2h(float a, float b) {
    uint32 ua = (uint32)__builtin_bit_cast(unsigned short, (_Float16)a);
    uint32 ub = (uint32)__builtin_bit_cast(unsigned short, (_Float16)b);
    return ua | (ub << 16);
}
__device__ __forceinline__ float2 unpack2h(uint32 w) {
    h2 h = __builtin_bit_cast(h2, w);
    return make_float2((float)h[0], (float)h[1]);
}

// ---- edge_index format detection: int64 rows have zero high words ----------
__global__ void detect_fmt(const int* __restrict__ ei, int nchecks, int* flag) {
    int t = blockIdx.x * blockDim.x + threadIdx.x;
    int acc = 0;
    for (int i = t; i < nchecks; i += blockDim.x * gridDim.x)
        acc |= ei[2 * i + 1];
    if (acc) atomicOr(flag, 1);   // nonzero => plain int32 layout
}

__device__ __forceinline__ int load_src(const int* ei, int e, int E, int is64) {
    return is64 ? ei[2 * e] : ei[e];
}
__device__ __forceinline__ int load_dst(const int* ei, int e, int E, int is64) {
    return is64 ? ei[2 * E + 2 * e] : ei[E + e];
}

// ---- CSR build: bucketed, atomic-free (LDS atomics only) -------------------
__global__ void hist_pack(const int* __restrict__ ei, int* __restrict__ bhT,
                          uint32* __restrict__ pc, int E, int nblk, int NB,
                          const int* __restrict__ flag) {
    __shared__ int h[MAXNB];
    int blk = blockIdx.x, tid = threadIdx.x;
    for (int i = tid; i < NB; i += 256) h[i] = 0;
    __syncthreads();
    int is64 = (*flag == 0);
    int e1 = blk * CHUNK + CHUNK; if (e1 > E) e1 = E;
    for (int e = blk * CHUNK + tid; e < e1; e += 256) {
        int s = load_src(ei, e, E, is64);
        int d = load_dst(ei, e, E, is64);
        pc[e] = (uint32)s | ((uint32)d << 16);
        atomicAdd(&h[d >> 7], 1);
    }
    __syncthreads();
    for (int i = tid; i < NB; i += 256) bhT[i * nblk + blk] = h[i];
}

__global__ void scan_blocks(const int* __restrict__ counts, int* __restrict__ partial,
                            int* __restrict__ blockSums, int n) {
    int tid = threadIdx.x;                 // 256
    int base = blockIdx.x * 1024 + tid * 4;
    int4 c = make_int4(0, 0, 0, 0);
    if (base + 3 < n) c = *(const int4*)&counts[base];
    else {
        if (base + 0 < n) c.x = counts[base + 0];
        if (base + 1 < n) c.y = counts[base + 1];
        if (base + 2 < n) c.z = counts[base + 2];
        if (base + 3 < n) c.w = counts[base + 3];
    }
    int s1 = c.x, s2 = s1 + c.y, s3 = s2 + c.z, s4 = s3 + c.w;
    int lane = tid & 63, wave = tid >> 6;
    int v = s4;
#pragma unroll
    for (int off = 1; off < 64; off <<= 1) {
        int t = __shfl_up(v, off);
        if (lane >= off) v += t;
    }
    __shared__ int wsum[4];
    if (lane == 63) wsum[wave] = v;
    __syncthreads();
    int wpre = 0;
    for (int w = 0; w < wave; ++w) wpre += wsum[w];
    int pre = wpre + v - s4;
    if (base + 0 < n) partial[base + 0] = pre + s1;
    if (base + 1 < n) partial[base + 1] = pre + s2;
    if (base + 2 < n) partial[base + 2] = pre + s3;
    if (base + 3 < n) partial[base + 3] = pre + s4;
    if (tid == 255) blockSums[blockIdx.x] = wsum[0] + wsum[1] + wsum[2] + wsum[3];
}

__global__ void scan_sums(int* __restrict__ bs, int nb) {
    int lane = threadIdx.x;                // 64
    int carry = 0;
    for (int b0 = 0; b0 < nb; b0 += 64) {
        int i = b0 + lane;
        int val = (i < nb) ? bs[i] : 0;
        int v = val;
#pragma unroll
        for (int off = 1; off < 64; off <<= 1) {
            int t = __shfl_up(v, off);
            if (lane >= off) v += t;
        }
        if (i < nb) bs[i] = carry + v - val;   // exclusive
        carry += __shfl(v, 63);
    }
}

__global__ void make_excl(const int* __restrict__ bh, const int* __restrict__ partial,
                          const int* __restrict__ bs, int* __restrict__ ebase, int n) {
    int i = blockIdx.x * 256 + threadIdx.x;
    if (i >= n) return;
    ebase[i] = partial[i] + bs[i >> 10] - bh[i];   // exclusive global scan
}

__global__ void bucket_scatter(const uint32* __restrict__ pc, const int* __restrict__ ebase,
                               uint32* __restrict__ pairs, int E, int nblk, int NB) {
    __shared__ int cur[MAXNB];
    int blk = blockIdx.x, tid = threadIdx.x;
    for (int i = tid; i < NB; i += 256) cur[i] = ebase[i * nblk + blk];
    __syncthreads();
    int e1 = blk * CHUNK + CHUNK; if (e1 > E) e1 = E;
    for (int e = blk * CHUNK + tid; e < e1; e += 256) {
        uint32 w = pc[e];
        int pos = atomicAdd(&cur[w >> 23], 1);   // bucket = dst >> 7
        pairs[pos] = w;
    }
}

__global__ void bucket_finalize(const uint32* __restrict__ pairs,
                                const int* __restrict__ ebase, int nblk, int NB,
                                int* __restrict__ csr_src, int* __restrict__ offsets,
                                int N, int E) {
    __shared__ int hist[NPB];
    __shared__ int cur[NPB];
    int b = blockIdx.x, tid = threadIdx.x;
    int n0 = b * NPB;
    int cnt = N - n0; if (cnt > NPB) cnt = NPB;
    if (cnt <= 0) return;
    int estart = ebase[b * nblk];
    int eend = (b + 1 < NB) ? ebase[(b + 1) * nblk] : E;
    for (int i = tid; i < cnt; i += 256) hist[i] = 0;
    __syncthreads();
    for (int e = estart + tid; e < eend; e += 256)
        atomicAdd(&hist[(int)(pairs[e] >> 16) - n0], 1);
    __syncthreads();
    if (tid == 0) {
        int run = estart;
        for (int i = 0; i < cnt; ++i) {
            cur[i] = run;
            offsets[n0 + i] = run;
            run += hist[i];
        }
    }
    if (b == 0 && tid == 1) offsets[N] = E;
    __syncthreads();
    for (int e = estart + tid; e < eend; e += 256) {
        uint32 w = pairs[e];
        int pos = atomicAdd(&cur[(int)(w >> 16) - n0], 1);
        csr_src[pos] = (int)(w & 0xFFFFu);
    }
}

// ---- W prep: bf16 hi/lo split, [col][k] layout, XOR-swizzled ---------------
__global__ void prep_w(const float* W0, const float* W1, const float* W2,
                       const float* W3, const float* W4, const float* W5,
                       const float* W6, const float* W7, const float* W8,
                       const float* W9, const float* W10, const float* W11,
                       uint32* __restrict__ wpack) {
    const float* Wm;
    switch (blockIdx.x) {
        case 0: Wm = W0; break;  case 1: Wm = W1; break;
        case 2: Wm = W2; break;  case 3: Wm = W3; break;
        case 4: Wm = W4; break;  case 5: Wm = W5; break;
        case 6: Wm = W6; break;  case 7: Wm = W7; break;
        case 8: Wm = W8; break;  case 9: Wm = W9; break;
        case 10: Wm = W10; break; default: Wm = W11; break;
    }
    int layer = blockIdx.x >> 2, mat = blockIdx.x & 3;
    uint32* hiB = wpack + layer * 16384;
    uint32* loB = hiB + 8192;
    int d = threadIdx.x & 63;
    int cg = threadIdx.x >> 6;
    int col = mat * 64 + d;
    for (int kw = cg; kw < 32; kw += 4) {
        float w0 = Wm[(2 * kw) * 64 + d];
        float w1 = Wm[(2 * kw + 1) * 64 + d];
        unsigned short h0 = bf16_rne(w0);
        unsigned short h1 = bf16_rne(w1);
        float r0 = w0 - __uint_as_float(((uint32)h0) << 16);
        float r1 = w1 - __uint_as_float(((uint32)h1) << 16);
        unsigned short l0 = bf16_rne(r0);
        unsigned short l1 = bf16_rne(r1);
        int sw = ((kw * 4) ^ ((col & 7) << 4)) >> 2;
        hiB[col * 32 + sw] = (uint32)h0 | ((uint32)h1 << 16);
        loB[col * 32 + sw] = (uint32)l0 | ((uint32)l1 << 16);
    }
}

// ---- MFMA q/kv/s GEMM ------------------------------------------------------
// Two-stage 32KB LDS (hi weights -> alo*bhi + ahi*bhi; lo weights -> ahi*blo).
// Epilogue (R13): stage q/s/k fp16 + v bf16 (4 x 8KB = 32KB) into the dead
// weight LDS with a 32B-block XOR swizzle keyed on (lr>>2)&3 (4 row-groups
// -> disjoint bank sets, only free 2-way merging), then linear ds_read_b128
// + fully coalesced 16B global stores.
template <int IN16>
__launch_bounds__(256)
__global__ void gemm_mfma(const void* __restrict__ xv, const uint32* __restrict__ wpackL,
                          const float* __restrict__ bq, const float* __restrict__ bk,
                          const float* __restrict__ bv, const float* __restrict__ bs,
                          ushort16* __restrict__ qh, float* __restrict__ kv,
                          ushort16* __restrict__ sh, int n) {
    __shared__ uint32 wlds[8192];   // 32 KiB, weights then output staging
    int tid = threadIdx.x;
    int lane = tid & 63, wave = tid >> 6;
    int row0 = blockIdx.x * 64 + wave * 16;
    int arow = row0 + (lane & 15);
    int kgrp = (lane >> 4) * 8;
    bool rowok = arow < n;

    bf16x8 ahi[2], alo[2];
#pragma unroll
    for (int st = 0; st < 2; ++st) {
        float xs[8];
        if (IN16) {
            const ushort16* xr = (const ushort16*)xv + (size_t)(rowok ? arow : 0) * D64;
            uint4 xw = rowok ? *(const uint4*)(xr + st * 32 + kgrp)
                             : make_uint4(0, 0, 0, 0);
            float2 p0 = unpack2h(xw.x), p1 = unpack2h(xw.y);
            float2 p2 = unpack2h(xw.z), p3 = unpack2h(xw.w);
            xs[0] = p0.x; xs[1] = p0.y; xs[2] = p1.x; xs[3] = p1.y;
            xs[4] = p2.x; xs[5] = p2.y; xs[6] = p3.x; xs[7] = p3.y;
        } else {
            const float* xr = (const float*)xv + (size_t)(rowok ? arow : 0) * D64;
            float4 xa = rowok ? *(const float4*)(xr + st * 32 + kgrp)
                              : make_float4(0.f, 0.f, 0.f, 0.f);
            float4 xb = rowok ? *(const float4*)(xr + st * 32 + kgrp + 4)
                              : make_float4(0.f, 0.f, 0.f, 0.f);
            xs[0] = xa.x; xs[1] = xa.y; xs[2] = xa.z; xs[3] = xa.w;
            xs[4] = xb.x; xs[5] = xb.y; xs[6] = xb.z; xs[7] = xb.w;
        }
#pragma unroll
        for (int j = 0; j < 8; ++j) {
            unsigned short h = bf16_rne(xs[j]);
            float rem = xs[j] - __uint_as_float(((uint32)h) << 16);
            ahi[st][j] = (short)h;
            alo[st][j] = (short)bf16_rne(rem);
        }
    }

    f32x4 acc[16];
#pragma unroll
    for (int t = 0; t < 16; ++t) acc[t] = f32x4{0.f, 0.f, 0.f, 0.f};

    // stage 1: hi weights -> alo*bhi + ahi*bhi
#pragma unroll
    for (int r = 0; r < 8; ++r) {
        int w4 = r * 1024 + tid * 4;
        *(uint4*)&wlds[w4] = *(const uint4*)&wpackL[w4];
    }
    __syncthreads();
#pragma unroll
    for (int t = 0; t < 16; ++t) {
        int col = t * 16 + (lane & 15);
#pragma unroll
        for (int st = 0; st < 2; ++st) {
            int kidx = st * 32 + kgrp;
            int boff = col * 128 + ((kidx * 2) ^ ((col & 7) << 4));
            bf16x8 bhi = *(const bf16x8*)((const char*)wlds + boff);
            acc[t] = __builtin_amdgcn_mfma_f32_16x16x32_bf16(alo[st], bhi, acc[t], 0, 0, 0);
            acc[t] = __builtin_amdgcn_mfma_f32_16x16x32_bf16(ahi[st], bhi, acc[t], 0, 0, 0);
        }
    }
    __syncthreads();
    // stage 2: lo weights -> ahi*blo
#pragma unroll
    for (int r = 0; r < 8; ++r) {
        int w4 = r * 1024 + tid * 4;
        *(uint4*)&wlds[w4] = *(const uint4*)&wpackL[8192 + w4];
    }
    __syncthreads();
#pragma unroll
    for (int t = 0; t < 16; ++t) {
        int col = t * 16 + (lane & 15);
#pragma unroll
        for (int st = 0; st < 2; ++st) {
            int kidx = st * 32 + kgrp;
            int boff = col * 128 + ((kidx * 2) ^ ((col & 7) << 4));
            bf16x8 blo = *(const bf16x8*)((const char*)wlds + boff);
            acc[t] = __builtin_amdgcn_mfma_f32_16x16x32_bf16(ahi[st], blo, acc[t], 0, 0, 0);
        }
    }
    __syncthreads();   // all waves done reading weights; reuse wlds for outputs

    // ---- epilogue stage A: per-value ds_write_b16 into swizzled staging ----
    // sections (halfword base): q 0 | s 4096 | k 8192 | v 12288
    unsigned short* ow = (unsigned short*)wlds;
    int c16 = lane & 15;
    int lrb = wave * 16 + ((lane >> 4) << 2);   // + r = local row
#pragma unroll
    for (int t = 0; t < 4; ++t) {
        float bbq = bq[t * 16 + c16];
        float bbs = bs[t * 16 + c16];
        float bkk = bk[t * 16 + c16];
        float bvv = bv[t * 16 + c16];
        int col = t * 16 + c16;
#pragma unroll
        for (int r = 0; r < 4; ++r) {
            int lr = lrb + r;
            int s4 = (lr >> 2) & 3;                 // 32B-block swizzle key
            int h = lr * 64 + (col ^ (s4 << 4));
            float qval = (acc[t][r] + bbq) * 0.125f;
            float sval = acc[12 + t][r] + bbs;
            float kval = acc[4 + t][r] + bkk;
            float vval = acc[8 + t][r] + bvv;
            ow[h]         = __builtin_bit_cast(unsigned short, (_Float16)qval);
            ow[4096 + h]  = __builtin_bit_cast(unsigned short, (_Float16)sval);
            ow[8192 + h]  = __builtin_bit_cast(unsigned short, (_Float16)kval);
            ow[12288 + h] = bf16_rne(vval);
        }
    }
    __syncthreads();

    // ---- epilogue stage B: linear ds_read_b128 + coalesced global stores ---
    // word-layout per section: 64 rows x 32 words; thread tid covers words
    // tid*4 (+u*1024): LDS reads perfectly linear, global stores dense.
#pragma unroll
    for (int u = 0; u < 2; ++u) {
        int pword = tid * 4 + u * 1024;
        int row_l = pword >> 5;
        int b = (pword >> 3) & 3;                   // physical 32B block
        int halfsel = (pword >> 2) & 1;
        int bl = b ^ ((row_l >> 2) & 3);            // un-swizzle
        int lwoff = bl * 8 + halfsel * 4;           // logical word in row
        int row_g = blockIdx.x * 64 + row_l;
        if (row_g < n) {
            uint4 qv4 = *(const uint4*)&wlds[pword];
            uint4 sv4 = *(const uint4*)&wlds[2048 + pword];
            uint4 kk4 = *(const uint4*)&wlds[4096 + pword];
            uint4 vv4 = *(const uint4*)&wlds[6144 + pword];
            *(uint4*)((uint32*)(qh + (size_t)row_g * D64) + lwoff) = qv4;
            *(uint4*)((uint32*)(sh + (size_t)row_g * D64) + lwoff) = sv4;
            uint32* rowp = (uint32*)(kv + (size_t)row_g * KVF);
            *(uint4*)(rowp + lwoff) = kk4;
            *(uint4*)(rowp + 32 + lwoff) = vv4;
        }
    }
}

// ---- fused edge-score + online-softmax aggregation + epilogue --------------
// Wave = 1 node; 8 groups x 8 lanes; 256B kv-row gather; fdot2 fp16 scores
// (q pre-scaled at gemm); raw v_exp/v_rcp; butterfly merge.
// MODE 1: outh = silu(t) fp16   MODE 2: outh = silu(t + xin) fp16 (in-place)
// MODE 3: outf = t + 0.1*z fp32
template <int MODE>
__launch_bounds__(256)
__global__ void agg_fused(const ushort16* __restrict__ qh, const float* __restrict__ kv,
                          const int* __restrict__ csr_src,
                          const int* __restrict__ offsets,
                          const ushort16* __restrict__ sbh, const ushort16* __restrict__ xinh,
                          const float* __restrict__ z, void* __restrict__ outp, int n) {
    int node = blockIdx.x * 4 + (threadIdx.x >> 6);
    if (node >= n) return;
    int lane = threadIdx.x & 63;
    int grp = lane >> 3, l8 = lane & 7;
    int start = offsets[node], end = offsets[node + 1];
    size_t co2 = (size_t)node * D64 + l8 * 8;   // halfword index
    uint4 sw = *(const uint4*)(sbh + co2);
    float2 s0 = unpack2h(sw.x), s1 = unpack2h(sw.y);
    float2 s2 = unpack2h(sw.z), s3 = unpack2h(sw.w);
    float4 ta = make_float4(s0.x, s0.y, s1.x, s1.y);
    float4 tb = make_float4(s2.x, s2.y, s3.x, s3.y);

    if (end > start) {
        uint4 qw = *(const uint4*)(qh + co2);
        h2 hq0 = __builtin_bit_cast(h2, qw.x);
        h2 hq1 = __builtin_bit_cast(h2, qw.y);
        h2 hq2 = __builtin_bit_cast(h2, qw.z);
        h2 hq3 = __builtin_bit_cast(h2, qw.w);
        float m = -3.0e38f, den = 0.f;
        float4 aa = make_float4(0.f, 0.f, 0.f, 0.f);
        float4 ab = make_float4(0.f, 0.f, 0.f, 0.f);

        int i = start + grp;
        int idx0 = (i < end) ? i : start;
        int sj0 = csr_src[idx0];
        const float* kp0 = kv + (size_t)sj0 * KVF;
        float4 kw = *(const float4*)(kp0 + l8 * 4);
        float4 vw = *(const float4*)(kp0 + 32 + l8 * 4);

        while (i < end) {
            int inext = i + 8;
            int idx1 = (inext < end) ? inext : start;
            int sj1 = csr_src[idx1];
            const float* kp1 = kv + (size_t)sj1 * KVF;
            float4 kw1 = *(const float4*)(kp1 + l8 * 4);
            float4 vw1 = *(const float4*)(kp1 + 32 + l8 * 4);

            float p = __builtin_amdgcn_fdot2(hq0, __builtin_bit_cast(h2, kw.x),
                                             0.f, false);
            p = __builtin_amdgcn_fdot2(hq1, __builtin_bit_cast(h2, kw.y), p, false);
            p = __builtin_amdgcn_fdot2(hq2, __builtin_bit_cast(h2, kw.z), p, false);
            p = __builtin_amdgcn_fdot2(hq3, __builtin_bit_cast(h2, kw.w), p, false);
            p += __shfl_xor(p, 1, 8);
            p += __shfl_xor(p, 2, 8);
            p += __shfl_xor(p, 4, 8);
            float nm = fmaxf(m, p);
            float f  = fexp(m - nm);
            float e  = fexp(p - nm);
            den = den * f + e;
            unsigned int u0 = __float_as_uint(vw.x), u1 = __float_as_uint(vw.y);
            unsigned int u2 = __float_as_uint(vw.z), u3 = __float_as_uint(vw.w);
            float v0 = __uint_as_float(u0 << 16), v1 = __uint_as_float(u0 & 0xFFFF0000u);
            float v2 = __uint_as_float(u1 << 16), v3 = __uint_as_float(u1 & 0xFFFF0000u);
            float v4 = __uint_as_float(u2 << 16), v5 = __uint_as_float(u2 & 0xFFFF0000u);
            float v6 = __uint_as_float(u3 << 16), v7 = __uint_as_float(u3 & 0xFFFF0000u);
            aa.x = aa.x * f + e * v0; aa.y = aa.y * f + e * v1;
            aa.z = aa.z * f + e * v2; aa.w = aa.w * f + e * v3;
            ab.x = ab.x * f + e * v4; ab.y = ab.y * f + e * v5;
            ab.z = ab.z * f + e * v6; ab.w = ab.w * f + e * v7;
            m = nm;
            kw = kw1; vw = vw1;
            i = inext;
        }
        float M = fmaxf(m, __shfl_xor(m, 8));
        M = fmaxf(M, __shfl_xor(M, 16));
        M = fmaxf(M, __shfl_xor(M, 32));
        float f = fexp(m - M);
        float dd = den * f;
        dd += __shfl_xor(dd, 8); dd += __shfl_xor(dd, 16); dd += __shfl_xor(dd, 32);
        aa.x *= f; aa.y *= f; aa.z *= f; aa.w *= f;
        ab.x *= f; ab.y *= f; ab.z *= f; ab.w *= f;
        aa.x += __shfl_xor(aa.x, 8); aa.x += __shfl_xor(aa.x, 16); aa.x += __shfl_xor(aa.x, 32);
        aa.y += __shfl_xor(aa.y, 8); aa.y += __shfl_xor(aa.y, 16); aa.y += __shfl_xor(aa.y, 32);
        aa.z += __shfl_xor(aa.z, 8); aa.z += __shfl_xor(aa.z, 16); aa.z += __shfl_xor(aa.z, 32);
        aa.w += __shfl_xor(aa.w, 8); aa.w += __shfl_xor(aa.w, 16); aa.w += __shfl_xor(aa.w, 32);
        ab.x += __shfl_xor(ab.x, 8); ab.x += __shfl_xor(ab.x, 16); ab.x += __shfl_xor(ab.x, 32);
        ab.y += __shfl_xor(ab.y, 8); ab.y += __shfl_xor(ab.y, 16); ab.y += __shfl_xor(ab.y, 32);
        ab.z += __shfl_xor(ab.z, 8); ab.z += __shfl_xor(ab.z, 16); ab.z += __shfl_xor(ab.z, 32);
        ab.w += __shfl_xor(ab.w, 8); ab.w += __shfl_xor(ab.w, 16); ab.w += __shfl_xor(ab.w, 32);
        float inv = frcp(dd);
        ta.x += aa.x * inv; ta.y += aa.y * inv; ta.z += aa.z * inv; ta.w += aa.w * inv;
        tb.x += ab.x * inv; tb.y += ab.y * inv; tb.z += ab.z * inv; tb.w += ab.w * inv;
    }
    if (MODE == 1) {
        ta.x *= frcp(1.f + fexp(-ta.x)); ta.y *= frcp(1.f + fexp(-ta.y));
        ta.z *= frcp(1.f + fexp(-ta.z)); ta.w *= frcp(1.f + fexp(-ta.w));
        tb.x *= frcp(1.f + fexp(-tb.x)); tb.y *= frcp(1.f + fexp(-tb.y));
        tb.z *= frcp(1.f + fexp(-tb.z)); tb.w *= frcp(1.f + fexp(-tb.w));
    } else if (MODE == 2) {
        uint4 xw = *(const uint4*)(xinh + co2);
        float2 x0 = unpack2h(xw.x), x1 = unpack2h(xw.y);
        float2 x2 = unpack2h(xw.z), x3 = unpack2h(xw.w);
        float u;
        u = ta.x + x0.x; ta.x = u * frcp(1.f + fexp(-u));
        u = ta.y + x0.y; ta.y = u * frcp(1.f + fexp(-u));
        u = ta.z + x1.x; ta.z = u * frcp(1.f + fexp(-u));
        u = ta.w + x1.y; ta.w = u * frcp(1.f + fexp(-u));
        u = tb.x + x2.x; tb.x = u * frcp(1.f + fexp(-u));
        u = tb.y + x2.y; tb.y = u * frcp(1.f + fexp(-u));
        u = tb.z + x3.x; tb.z = u * frcp(1.f + fexp(-u));
        u = tb.w + x3.y; tb.w = u * frcp(1.f + fexp(-u));
    } else {
        size_t cof = (size_t)node * D64 + l8 * 8;
        const float4 za = *(const float4*)(z + cof);
        const float4 zb = *(const float4*)(z + cof + 4);
        ta.x += 0.1f * za.x; ta.y += 0.1f * za.y;
        ta.z += 0.1f * za.z; ta.w += 0.1f * za.w;
        tb.x += 0.1f * zb.x; tb.y += 0.1f * zb.y;
        tb.z += 0.1f * zb.z; tb.w += 0.1f * zb.w;
    }
    if (grp == 0) {
        if (MODE == 3) {
            float* outf = (float*)outp;
            size_t cof = (size_t)node * D64 + l8 * 8;
            *(float4*)(outf + cof) = ta;
            *(float4*)(outf + cof + 4) = tb;
        } else {
            ushort16* outh = (ushort16*)outp;
            uint4 ow;
            ow.x = pack2h(ta.x, ta.y); ow.y = pack2h(ta.z, ta.w);
            ow.z = pack2h(tb.x, tb.y); ow.w = pack2h(tb.z, tb.w);
            *(uint4*)(outh + co2) = ow;
        }
    }
}

// ---------------------------------------------------------------------------
extern "C" void kernel_launch(void* const* d_in, const int* in_sizes, int n_in,
                              void* d_out, int out_size, void* d_ws, size_t ws_size,
                              hipStream_t stream) {
    const float* x = (const float*)d_in[0];
    const int* ei  = (const int*)d_in[1];
    const float* z = (const float*)d_in[2];
    const float* W[3][4];
    const float* B[3][4];
    for (int l = 0; l < 3; ++l)
        for (int m = 0; m < 4; ++m) {
            W[l][m] = (const float*)d_in[3 + l * 8 + m * 2];
            B[l][m] = (const float*)d_in[3 + l * 8 + m * 2 + 1];
        }
    int N = in_sizes[0] / D64;
    int E = in_sizes[1] / 2;
    size_t ND = (size_t)N * D64;

    int NB   = (N + NPB - 1) / NPB;          // buckets (391)
    int nblk = (E + CHUNK - 1) / CHUNK;      // edge chunks (196)
    int nscan = NB * nblk;                   // ~77k
    int nb2  = (nscan + 1023) / 1024;        // scan blocks (~75)

    char* p = (char*)d_ws;
    auto alloc = [&](size_t bytes) {
        char* r = p;
        p += (bytes + 255) & ~(size_t)255;
        return r;
    };
    ushort16* qh   = (ushort16*)alloc(ND * 2);
    ushort16* sbh  = (ushort16*)alloc(ND * 2);
    ushort16* hAh  = (ushort16*)alloc(ND * 2);
    float* kv      = (float*)alloc((size_t)N * KVF * 4);
    int* csr_src   = (int*)alloc((size_t)E * 4);
    uint32* pc     = (uint32*)alloc((size_t)E * 4);
    uint32* pairs  = (uint32*)alloc((size_t)E * 4);
    int* offsets   = (int*)alloc((size_t)(N + 1) * 4);
    int* bhT       = (int*)alloc((size_t)nscan * 4);
    int* partial   = (int*)alloc((size_t)nscan * 4);
    int* ebase     = (int*)alloc((size_t)nscan * 4);
    int* blockSums = (int*)alloc((size_t)nb2 * 4);
    uint32* wpack  = (uint32*)alloc(3 * 16384 * 4);
    int* flag      = (int*)alloc(4);
    float* outp    = (float*)d_out;

    hipMemsetAsync(flag, 0, 4, stream);
    int nchecks = E < 4096 ? E : 4096;
    detect_fmt<<<1, 256, 0, stream>>>(ei, nchecks, flag);
    prep_w<<<12, 256, 0, stream>>>(W[0][0], W[0][1], W[0][2], W[0][3],
                                   W[1][0], W[1][1], W[1][2], W[1][3],
                                   W[2][0], W[2][1], W[2][2], W[2][3], wpack);
    hist_pack<<<nblk, 256, 0, stream>>>(ei, bhT, pc, E, nblk, NB, flag);
    scan_blocks<<<nb2, 256, 0, stream>>>(bhT, partial, blockSums, nscan);
    scan_sums<<<1, 64, 0, stream>>>(blockSums, nb2);
    make_excl<<<(nscan + 255) / 256, 256, 0, stream>>>(bhT, partial, blockSums,
                                                       ebase, nscan);
    bucket_scatter<<<nblk, 256, 0, stream>>>(pc, ebase, pairs, E, nblk, NB);
    bucket_finalize<<<NB, 256, 0, stream>>>(pairs, ebase, nblk, NB,
                                            csr_src, offsets, N, E);

    int gemm_grid = (N + 63) / 64;
    int node_grid = (N + 3) / 4;

    // layer 1: x (fp32) -> hAh (fp16), silu
    gemm_mfma<0><<<gemm_grid, 256, 0, stream>>>(x, wpack, B[0][0], B[0][1],
                                                B[0][2], B[0][3], qh, kv, sbh, N);
    agg_fused<1><<<node_grid, 256, 0, stream>>>(qh, kv, csr_src, offsets, sbh,
                                                nullptr, nullptr, hAh, N);
    // layer 2: hAh -> hAh (residual + silu, in-place)
    gemm_mfma<1><<<gemm_grid, 256, 0, stream>>>(hAh, wpack + 16384, B[1][0], B[1][1],
                                                B[1][2], B[1][3], qh, kv, sbh, N);
    agg_fused<2><<<node_grid, 256, 0, stream>>>(qh, kv, csr_src, offsets, sbh,
                                                hAh, nullptr, hAh, N);
    // layer 3: hAh -> out (fp32), + 0.1*z
    gemm_mfma<1><<<gemm_grid, 256, 0, stream>>>(hAh, wpack + 32768, B[2][0], B[2][1],
                                                B[2][2], B[2][3], qh, kv, sbh, N);
    agg_fused<3><<<node_grid, 256, 0, stream>>>(qh, kv, csr_src, offsets, sbh,
                                                nullptr, z, outp, N);
}